// Round 13
// baseline (250.730 us; speedup 1.0000x reference)
//
#include <hip/hip_runtime.h>
#include <math.h>

using f32x4  = __attribute__((ext_vector_type(4))) float;
using f16x8  = __attribute__((ext_vector_type(8))) _Float16;
using u16x8  = __attribute__((ext_vector_type(8))) unsigned short;
using u16x4  = __attribute__((ext_vector_type(4))) unsigned short;

static __device__ __forceinline__ unsigned short f2h(float f) {
  _Float16 h = (_Float16)f;
  return __builtin_bit_cast(unsigned short, h);
}

static __device__ __forceinline__ f32x4 mfma_f16(f16x8 a, f16x8 b, f32x4 c) {
  return __builtin_amdgcn_mfma_f32_16x16x32_f16(a, b, c, 0, 0, 0);
}

// async global->LDS, 16B per lane. LDS dest is wave-uniform base; HW appends
// lane*16.
static __device__ __forceinline__ void gll16(const void* g, void* l) {
  using GPtr = const unsigned int __attribute__((address_space(1)))*;
  using LPtr = unsigned int __attribute__((address_space(3)))*;
  __builtin_amdgcn_global_load_lds((GPtr)(unsigned long long)g,
                                   (LPtr)(unsigned)(unsigned long long)l,
                                   16, 0, 0);
}

// ---------------------------------------------------------------------------
// Wave-private 64x32 f16 slice, paired-row XOR layout (r7-proven 0-conflict):
// 32 lines x 128B; line L holds slice rows {2L, 2L+1}; logical 16B-slot
// q = (row&1)<<2 | kblock; physical slot p = q ^ (L&7).
// Stage: 4 x gll16 (1KB each), linear LDS dest + pre-swizzled global source
// (rule #21). Entirely self-staged per wave -> NO cross-wave barriers needed.
// ---------------------------------------------------------------------------
static __device__ __forceinline__ void stage_slice(unsigned short* dst,
                                                   const unsigned short* g,
                                                   size_t ld, int k0, int lane) {
  const int p = lane & 7, ll = lane >> 3;
#pragma unroll
  for (int i = 0; i < 4; ++i) {
    const int line = i * 8 + ll;
    const int q = p ^ (line & 7);
    gll16(g + (size_t)(2 * line + (q >> 2)) * ld + (k0 + ((q & 3) << 3)),
          dst + i * 512);
  }
}

// Fragment read from the slice: slice-local row in [0,64), kko in {0,8,16,24}.
static __device__ __forceinline__ f16x8 frag_slice(const unsigned short* s,
                                                   int row, int kko) {
  const int line = row >> 1;
  const int q = ((row & 1) << 2) | (kko >> 3);
  const int p = q ^ (line & 7);
  return *(const f16x8*)&s[line * 64 + p * 8];
}

// ---------------------------------------------------------------------------
// Wk/Wq [1024x1024] f32 -> f16, original layout, coalesced.
// ---------------------------------------------------------------------------
__global__ __launch_bounds__(256) void convert_wkq_kernel(
    const float* __restrict__ Wk, const float* __restrict__ Wq,
    unsigned short* __restrict__ Wkh, unsigned short* __restrict__ Wqh) {
  const int z = blockIdx.z;
  const float* W = z ? Wq : Wk;
  unsigned short* H = z ? Wqh : Wkh;
  const size_t base = (size_t)blockIdx.x * 4096 + threadIdx.x * 4;
#pragma unroll
  for (int k = 0; k < 4; ++k) {
    f32x4 v = *(const f32x4*)&W[base + k * 1024];
    u16x4 h;
#pragma unroll
    for (int e = 0; e < 4; ++e) h[e] = f2h(v[e]);
    *(u16x4*)&H[base + k * 1024] = h;
  }
}

// ---------------------------------------------------------------------------
// Wv [1024 i][1024 o] f32 -> WvT [1024 o][1024 i] f16 (transposed)
// ---------------------------------------------------------------------------
__global__ __launch_bounds__(256) void convert_wv_kernel(
    const float* __restrict__ Wv, unsigned short* __restrict__ WvT) {
  __shared__ float sW[64][65];
  const int ti = blockIdx.x * 64;
  const int tj = blockIdx.y * 64;
  const int tid = threadIdx.x;
#pragma unroll
  for (int it = 0; it < 4; ++it) {
    int idx = tid + it * 256;
    int r = idx >> 4, c = (idx & 15) << 2;
    f32x4 v = *(const f32x4*)&Wv[(size_t)(ti + r) * 1024 + tj + c];
    sW[r][c] = v[0]; sW[r][c + 1] = v[1]; sW[r][c + 2] = v[2]; sW[r][c + 3] = v[3];
  }
  __syncthreads();
#pragma unroll
  for (int it = 0; it < 4; ++it) {
    int idx = tid + it * 256;
    int ro = idx >> 4, ci = (idx & 15) << 2;
    u16x4 h;
#pragma unroll
    for (int e = 0; e < 4; ++e) h[e] = f2h(sW[ci + e][ro]);
    *(u16x4*)&WvT[(size_t)(tj + ro) * 1024 + ti + ci] = h;
  }
}

// ---------------------------------------------------------------------------
// X [8192 x 1024] f32 -> X_f16, coalesced. z: 0 = keys, 1 = queries, 2 = vals.
// ---------------------------------------------------------------------------
__global__ __launch_bounds__(256) void convert_x_kernel(
    const float* __restrict__ Xk, const float* __restrict__ Xq,
    const float* __restrict__ Xv, unsigned short* __restrict__ Xkh,
    unsigned short* __restrict__ Xqh, unsigned short* __restrict__ Xvh) {
  const int z = blockIdx.z;
  const float* X = (z == 0) ? Xk : (z == 1) ? Xq : Xv;
  unsigned short* H = (z == 0) ? Xkh : (z == 1) ? Xqh : Xvh;
  const size_t base = (size_t)blockIdx.x * 4096 + threadIdx.x * 4;
#pragma unroll
  for (int k = 0; k < 4; ++k) {
    f32x4 v = *(const f32x4*)&X[base + k * 1024];
    u16x4 h;
#pragma unroll
    for (int e = 0; e < 4; ++e) h[e] = f2h(v[e]);
    *(u16x4*)&H[base + k * 1024] = h;
  }
}

// ---------------------------------------------------------------------------
// f16 GEMM, wave-private-slice, ZERO-BARRIER counted-vmcnt pipeline.
// 128x128 tile, 4 waves (2x2). Each wave owns a PRIVATE 64x32 A-slice +
// 64x32 B-slice per buffer (8KB/wave/buf; 64KB total; 2 blocks/CU). A wave
// stages exactly the slices it reads -> no __syncthreads in the K-loop.
// Per step (BK=32): vmcnt(8) [self loads from 2 steps ago] -> ds_read +
// 16 MFMA -> lgkmcnt(0) [reads drained before overwrite] -> restage st+2.
// C = A * B^T, both K-major. XCD-chunked bijective swizzle (T1, m204).
// EPI: 0 = f32 C ; 2 = f16 C ; 3 = f16 transposed into VT[4][1024][2048].
// PACKED: lid%gx is a packed lower-triangle tile index.
// PVK: K-loop ends at (bm+1)*128; bm decode reversed (heavy tiles first).
// ---------------------------------------------------------------------------
template <int EPI, bool PACKED, bool PVK>
__global__ __launch_bounds__(256, 2) void gemm_pw_kernel(
    const unsigned short* __restrict__ Ah, const unsigned short* __restrict__ Bh,
    size_t lda, size_t ldb, int K,
    float* __restrict__ Cf, unsigned short* __restrict__ Ch, size_t ldc,
    size_t abatch, size_t bbatch, size_t cbatch) {
  __shared__ unsigned short smem[2][4][4096];  // [buf][wave][A 2048 | B 2048]

  // Bijective XCD-chunked swizzle over the full linearized grid (m204).
  int lid = blockIdx.x + gridDim.x * (blockIdx.y + gridDim.y * blockIdx.z);
  {
    const int n = gridDim.x * gridDim.y * gridDim.z;
    const int q = n >> 3, r = n & 7, x = lid & 7, k = lid >> 3;
    lid = (x < r ? x * (q + 1) : r * (q + 1) + (x - r) * q) + k;
  }
  int bm, bn, b;
  if constexpr (PACKED) {
    const int t = lid % gridDim.x;
    b = lid / gridDim.x;
    bm = (int)((sqrtf(8.f * (float)t + 1.f) - 1.f) * 0.5f);
    while ((bm + 1) * (bm + 2) / 2 <= t) ++bm;
    while (bm * (bm + 1) / 2 > t) --bm;
    bn = t - bm * (bm + 1) / 2;
  } else {
    bn = lid % gridDim.x;
    const int tmp = lid / gridDim.x;
    bm = tmp % gridDim.y;
    b = tmp / gridDim.y;
    if constexpr (PVK) bm = (int)gridDim.y - 1 - bm;  // heavy tiles first
  }
  const int tid = threadIdx.x, lane = tid & 63, wave = tid >> 6;
  const int wr = (wave >> 1) << 6, wc = (wave & 1) << 6;
  // Slice bases: this wave's 64 A-rows and 64 B-rows.
  const unsigned short* gA = Ah + abatch * b + (size_t)(bm * 128 + wr) * lda;
  const unsigned short* gB = Bh + bbatch * b + (size_t)(bn * 128 + wc) * ldb;
  const int kend = PVK ? (bm + 1) * 128 : K;
  const int nsteps = kend / 32;
  f32x4 acc[4][4] = {};
  const int frow = lane & 15, koff = (lane >> 4) << 3;

  unsigned short* myA[2] = {&smem[0][wave][0], &smem[1][wave][0]};
  unsigned short* myB[2] = {&smem[0][wave][2048], &smem[1][wave][2048]};
  auto stage_all = [&](int buf, int k0) {
    stage_slice(myA[buf], gA, lda, k0, lane);
    stage_slice(myB[buf], gB, ldb, k0, lane);
  };

  stage_all(0, 0);
  stage_all(1, 32);  // nsteps >= 4 always
  int cur = 0;
  for (int st = 0; st < nsteps; ++st) {
    if (st + 1 < nsteps) {
      asm volatile("s_waitcnt vmcnt(8)" ::: "memory");  // slice for buf[cur] ready
    } else {
      asm volatile("s_waitcnt vmcnt(0)" ::: "memory");
    }
    __builtin_amdgcn_sched_barrier(0);
    f16x8 fB[4];
#pragma unroll
    for (int j = 0; j < 4; ++j) fB[j] = frag_slice(myB[cur], j * 16 + frow, koff);
#pragma unroll
    for (int i = 0; i < 4; ++i) {
      const f16x8 a = frag_slice(myA[cur], i * 16 + frow, koff);
#pragma unroll
      for (int j = 0; j < 4; ++j) acc[i][j] = mfma_f16(a, fB[j], acc[i][j]);
    }
    asm volatile("s_waitcnt lgkmcnt(0)" ::: "memory");  // reads done before overwrite
    __builtin_amdgcn_sched_barrier(0);
    if (st + 2 < nsteps) stage_all(cur, (st + 2) * 32);
    cur ^= 1;
  }

  const int erow = bm * 128 + wr + ((lane >> 4) << 2);
  const int ecol = bn * 128 + wc + frow;
  if constexpr (EPI == 0) {
    float* C = Cf + cbatch * b;
#pragma unroll
    for (int i = 0; i < 4; ++i)
#pragma unroll
      for (int j = 0; j < 4; ++j)
#pragma unroll
        for (int e = 0; e < 4; ++e)
          C[(size_t)(erow + i * 16 + e) * ldc + (ecol + j * 16)] = acc[i][j][e];
  } else if constexpr (EPI == 3) {
    // Fused V-transpose: Ch is VT[4][1024 o][2048 s].
#pragma unroll
    for (int i = 0; i < 4; ++i)
#pragma unroll
      for (int j = 0; j < 4; ++j) {
        const int s = erow + i * 16;
        const int o = ecol + j * 16;
        u16x4 v;
#pragma unroll
        for (int e = 0; e < 4; ++e) v[e] = f2h(acc[i][j][e]);
        *(u16x4*)&Ch[((size_t)(s >> 11) * 1024 + o) * 2048 + (s & 2047)] = v;
      }
  } else {
    unsigned short* Cho = Ch + cbatch * b;
#pragma unroll
    for (int i = 0; i < 4; ++i)
#pragma unroll
      for (int j = 0; j < 4; ++j)
#pragma unroll
        for (int e = 0; e < 4; ++e)
          Cho[(size_t)(erow + i * 16 + e) * ldc + (ecol + j * 16)] =
              f2h(acc[i][j][e]);
  }
}

// ---------------------------------------------------------------------------
// Sum 4 split-K partials of MT (f32) -> MT plain f16. [1024x1024]
// ---------------------------------------------------------------------------
__global__ __launch_bounds__(256) void reduce_mt_kernel(
    const float* __restrict__ P, unsigned short* __restrict__ H) {
  const size_t base = ((size_t)blockIdx.x * 256 + threadIdx.x) * 4;
  f32x4 s = *(const f32x4*)&P[base];
#pragma unroll
  for (int z = 1; z < 4; ++z) {
    f32x4 v = *(const f32x4*)&P[(size_t)z * 1048576 + base];
    s[0] += v[0]; s[1] += v[1]; s[2] += v[2]; s[3] += v[3];
  }
  u16x4 h;
#pragma unroll
  for (int e = 0; e < 4; ++e) h[e] = f2h(s[e]);
  *(u16x4*)&H[base] = h;
}

// ---------------------------------------------------------------------------
// Row softmax with causal mask + 1/sqrt(d) scale. Writes f16 P in-place
// over the f32 scores buffer. Safe: reads complete before first barrier.
// ---------------------------------------------------------------------------
__global__ __launch_bounds__(256) void softmax_kernel(float* __restrict__ Sc) {
  const int row = blockIdx.x;  // b*2048 + q
  const int q = row & 2047;
  const int tid = threadIdx.x, lane = tid & 63, wave = tid >> 6;
  float* srow = Sc + (size_t)row * 2048;
  unsigned short* prow = (unsigned short*)srow;
  const int k0 = tid * 4, k1 = 1024 + tid * 4;
  f32x4 v0 = {}, v1 = {};
  if (k0 <= q) v0 = *(const f32x4*)(srow + k0);
  if (k1 <= q) v1 = *(const f32x4*)(srow + k1);
  float m = -3.0e38f;
#pragma unroll
  for (int e = 0; e < 4; ++e) {
    if (k0 + e <= q) m = fmaxf(m, v0[e]);
    if (k1 + e <= q) m = fmaxf(m, v1[e]);
  }
#pragma unroll
  for (int o = 32; o; o >>= 1) m = fmaxf(m, __shfl_xor(m, o));
  __shared__ float redm[4], reds[4];
  if (lane == 0) redm[wave] = m;
  __syncthreads();
  m = fmaxf(fmaxf(redm[0], redm[1]), fmaxf(redm[2], redm[3]));
  const float scale = 0.03125f;  // 1/sqrt(1024)
  float p[8];
  float s = 0.f;
#pragma unroll
  for (int e = 0; e < 4; ++e) {
    p[e] = (k0 + e <= q) ? __expf((v0[e] - m) * scale) : 0.f;
    p[4 + e] = (k1 + e <= q) ? __expf((v1[e] - m) * scale) : 0.f;
    s += p[e] + p[4 + e];
  }
#pragma unroll
  for (int o = 32; o; o >>= 1) s += __shfl_xor(s, o);
  if (lane == 0) reds[wave] = s;
  __syncthreads();
  s = reds[0] + reds[1] + reds[2] + reds[3];
  const float inv = 1.0f / s;
  u16x4 o0, o1;
#pragma unroll
  for (int e = 0; e < 4; ++e) {
    o0[e] = f2h(p[e] * inv);
    o1[e] = f2h(p[4 + e] * inv);
  }
  *(u16x4*)&prow[k0] = o0;
  *(u16x4*)&prow[k1] = o1;
}

// ---------------------------------------------------------------------------
extern "C" void kernel_launch(void* const* d_in, const int* in_sizes, int n_in,
                              void* d_out, int out_size, void* d_ws, size_t ws_size,
                              hipStream_t stream) {
  const float* Xk = (const float*)d_in[0];
  const float* Xv = (const float*)d_in[1];
  const float* Xq = (const float*)d_in[2];
  const float* Wk = (const float*)d_in[3];
  const float* Wv = (const float*)d_in[4];
  const float* Wq = (const float*)d_in[5];
  float* out = (float*)d_out;

  char* ws = (char*)d_ws;
  const size_t MB = 1024ull * 1024;
  // Liveness: everything in [0,64MB) is dead before scores -> Sc alias.
  unsigned short* Xqh   = (unsigned short*)(ws + 0);          // 16MB f16, dead after T
  unsigned short* Xvh   = (unsigned short*)(ws + 16 * MB);    // 16MB f16, dead after V
  unsigned short* Wkh   = (unsigned short*)(ws + 32 * MB);    // 2MB f16, dead after M
  unsigned short* Wqh   = (unsigned short*)(ws + 34 * MB);    // 2MB f16, dead after M
  unsigned short* MTh   = (unsigned short*)(ws + 40 * MB);    // 2MB f16, dead after T
  unsigned short* WvT   = (unsigned short*)(ws + 44 * MB);    // 2MB f16, dead after V
  float*          MTpart= (float*)(ws + 46 * MB);             // 16MB f32, dead after reduce
  unsigned short* Xkh   = (unsigned short*)(ws + 64 * MB);    // 16MB f16, live thru scores
  unsigned short* Th    = (unsigned short*)(ws + 80 * MB);    // 16MB f16, live thru scores
  unsigned short* VT    = (unsigned short*)(ws + 96 * MB);    // 16MB f16, live thru PV
  float*          Sc    = (float*)(ws + 0);                   // 64MB alias over dead region

  // --- precision prep (all f16) ---
  convert_wkq_kernel<<<dim3(256, 1, 2), 256, 0, stream>>>(Wk, Wq, Wkh, Wqh);
  convert_wv_kernel<<<dim3(16, 16), 256, 0, stream>>>(Wv, WvT);
  convert_x_kernel<<<dim3(2048, 1, 3), 256, 0, stream>>>(Xk, Xq, Xv, Xkh, Xqh, Xvh);

  // --- M^T = Wk_f16 . Wq_f16^T, split-K over 4 256-wide slices ---
  gemm_pw_kernel<0, false, false><<<dim3(8, 8, 4), 256, 0, stream>>>(
      Wkh, Wqh, 1024, 1024, 256, MTpart, nullptr, 1024, 256, 256,
      (size_t)1024 * 1024);
  reduce_mt_kernel<<<dim3(1024), 256, 0, stream>>>(MTpart, MTh);

  // --- T = Xq_f16 . MT^T (f16 out) ---
  gemm_pw_kernel<2, false, false><<<dim3(8, 64, 1), 256, 0, stream>>>(
      Xqh, MTh, 1024, 1024, 1024, nullptr, Th, 1024, 0, 0, 0);

  // --- V = Xv . Wv, epilogue writes VT (f16) directly ---
  gemm_pw_kernel<3, false, false><<<dim3(8, 64, 1), 256, 0, stream>>>(
      Xvh, WvT, 1024, 1024, 1024, nullptr, VT, 2048, 0, 0, 0);

  // --- scores = T_f16 . Xk_f16^T, packed lower-triangle, f32 out ---
  gemm_pw_kernel<0, true, false><<<dim3(136, 1, 4), 256, 0, stream>>>(
      Th, Xkh, 1024, 1024, 1024, Sc, nullptr, 2048, (size_t)2048 * 1024,
      (size_t)2048 * 1024, (size_t)2048 * 2048);

  softmax_kernel<<<dim3(8192), 256, 0, stream>>>(Sc);

  // --- out = P_f16 . V, P pitch 4096, VT K-major, K stops at diagonal;
  //     heavy (large-bm) tiles dispatch first ---
  gemm_pw_kernel<0, false, true><<<dim3(8, 16, 4), 256, 0, stream>>>(
      (const unsigned short*)Sc, VT, 4096, 2048, 2048, out, nullptr, 1024,
      (size_t)2048 * 4096, (size_t)1024 * 2048, (size_t)2048 * 1024);
}

// Round 14
// 177.028 us; speedup vs baseline: 1.4163x; 1.4163x over previous
//
#include <hip/hip_runtime.h>
#include <math.h>

using f32x4  = __attribute__((ext_vector_type(4))) float;
using f16x8  = __attribute__((ext_vector_type(8))) _Float16;
using u16x8  = __attribute__((ext_vector_type(8))) unsigned short;
using u16x4  = __attribute__((ext_vector_type(4))) unsigned short;

static __device__ __forceinline__ unsigned short f2h(float f) {
  _Float16 h = (_Float16)f;
  return __builtin_bit_cast(unsigned short, h);
}

static __device__ __forceinline__ f32x4 mfma_f16(f16x8 a, f16x8 b, f32x4 c) {
  return __builtin_amdgcn_mfma_f32_16x16x32_f16(a, b, c, 0, 0, 0);
}

// async global->LDS, 16B per lane. LDS dest is wave-uniform base; HW appends
// lane*16.
static __device__ __forceinline__ void gll16(const void* g, void* l) {
  using GPtr = const unsigned int __attribute__((address_space(1)))*;
  using LPtr = unsigned int __attribute__((address_space(3)))*;
  __builtin_amdgcn_global_load_lds((GPtr)(unsigned long long)g,
                                   (LPtr)(unsigned)(unsigned long long)l,
                                   16, 0, 0);
}

// Stage one [128][32] f16 tile, paired-row XOR layout (r7-proven 0-conflict):
// 64 lines x 128B; line L holds rows {2L, 2L+1}; logical 16B-slot
// q = (row&1)<<2 | kblock; physical slot p = q ^ (L&7).
// Linear LDS dest + pre-swizzled global source (rule #21).
// Wave w stages lines [16w, 16w+16): 2 x gll16 (1KB each).
static __device__ __forceinline__ void stage32(unsigned short* sdst,
                                               const unsigned short* g,
                                               size_t ld, int k0, int wave,
                                               int lane) {
  const int p = lane & 7, ll = lane >> 3;
#pragma unroll
  for (int i = 0; i < 2; ++i) {
    const int line = wave * 16 + i * 8 + ll;
    const int q = p ^ (line & 7);
    gll16(g + (size_t)(2 * line + (q >> 2)) * ld + (k0 + ((q & 3) << 3)),
          sdst + wave * 1024 + i * 512);
  }
}

// Fragment read matching stage32's layout: row in [0,128), kko in {0,8,16,24}.
static __device__ __forceinline__ f16x8 frag32(const unsigned short* s,
                                               int row, int kko) {
  const int line = row >> 1;
  const int q = ((row & 1) << 2) | (kko >> 3);
  const int p = q ^ (line & 7);
  return *(const f16x8*)&s[line * 64 + p * 8];
}

// ---------------------------------------------------------------------------
// Wk/Wq [1024x1024] f32 -> f16, original layout, coalesced.
// ---------------------------------------------------------------------------
__global__ __launch_bounds__(256) void convert_wkq_kernel(
    const float* __restrict__ Wk, const float* __restrict__ Wq,
    unsigned short* __restrict__ Wkh, unsigned short* __restrict__ Wqh) {
  const int z = blockIdx.z;
  const float* W = z ? Wq : Wk;
  unsigned short* H = z ? Wqh : Wkh;
  const size_t base = (size_t)blockIdx.x * 4096 + threadIdx.x * 4;
  f32x4 v[4];
#pragma unroll
  for (int k = 0; k < 4; ++k) v[k] = *(const f32x4*)&W[base + k * 1024];
#pragma unroll
  for (int k = 0; k < 4; ++k) {
    u16x4 h;
#pragma unroll
    for (int e = 0; e < 4; ++e) h[e] = f2h(v[k][e]);
    *(u16x4*)&H[base + k * 1024] = h;
  }
}

// ---------------------------------------------------------------------------
// Wv [1024 i][1024 o] f32 -> WvT [1024 o][1024 i] f16 (transposed)
// ---------------------------------------------------------------------------
__global__ __launch_bounds__(256) void convert_wv_kernel(
    const float* __restrict__ Wv, unsigned short* __restrict__ WvT) {
  __shared__ float sW[64][65];
  const int ti = blockIdx.x * 64;
  const int tj = blockIdx.y * 64;
  const int tid = threadIdx.x;
#pragma unroll
  for (int it = 0; it < 4; ++it) {
    int idx = tid + it * 256;
    int r = idx >> 4, c = (idx & 15) << 2;
    f32x4 v = *(const f32x4*)&Wv[(size_t)(ti + r) * 1024 + tj + c];
    sW[r][c] = v[0]; sW[r][c + 1] = v[1]; sW[r][c + 2] = v[2]; sW[r][c + 3] = v[3];
  }
  __syncthreads();
#pragma unroll
  for (int it = 0; it < 4; ++it) {
    int idx = tid + it * 256;
    int ro = idx >> 4, ci = (idx & 15) << 2;
    u16x4 h;
#pragma unroll
    for (int e = 0; e < 4; ++e) h[e] = f2h(sW[ci + e][ro]);
    *(u16x4*)&WvT[(size_t)(tj + ro) * 1024 + ti + ci] = h;
  }
}

// ---------------------------------------------------------------------------
// X [8192 x 1024] f32 -> X_f16, coalesced; 4 loads batched before 4 stores.
// z: 0 = keys, 1 = queries, 2 = values.
// ---------------------------------------------------------------------------
__global__ __launch_bounds__(256) void convert_x_kernel(
    const float* __restrict__ Xk, const float* __restrict__ Xq,
    const float* __restrict__ Xv, unsigned short* __restrict__ Xkh,
    unsigned short* __restrict__ Xqh, unsigned short* __restrict__ Xvh) {
  const int z = blockIdx.z;
  const float* X = (z == 0) ? Xk : (z == 1) ? Xq : Xv;
  unsigned short* H = (z == 0) ? Xkh : (z == 1) ? Xqh : Xvh;
  const size_t base = (size_t)blockIdx.x * 4096 + threadIdx.x * 4;
  f32x4 v[4];
#pragma unroll
  for (int k = 0; k < 4; ++k) v[k] = *(const f32x4*)&X[base + k * 1024];
#pragma unroll
  for (int k = 0; k < 4; ++k) {
    u16x4 h;
#pragma unroll
    for (int e = 0; e < 4; ++e) h[e] = f2h(v[k][e]);
    *(u16x4*)&H[base + k * 1024] = h;
  }
}

// ---------------------------------------------------------------------------
// f16 GEMM, r8-verified deep 2-buffer counted-vmcnt pipeline, BK=32:
// 128x128 tile, 4 waves, 2 tiles/buf x 2 buf = 32KB LDS -> 4 blocks/CU
// (launch_bounds(256,4)). Per step: vmcnt(4) [the 4 loads issued 2 steps
// ago] -> s_barrier -> ds_read + 16 MFMA -> lgkmcnt(0) -> s_barrier ->
// restage buf[cur] for st+2 (4 loads; never drain to 0 mid-loop).
// C = A * B^T, both K-major. XCD-chunked bijective swizzle (T1, m204).
// EPI: 0 = f32 C ; 2 = f16 C ; 3 = f16 transposed into VT[4][1024][2048].
// PACKED: lid%gx is a packed lower-triangle tile index.
// PVK: K-loop ends at (bm+1)*128; bm decode reversed (heavy tiles first).
// ---------------------------------------------------------------------------
template <int EPI, bool PACKED, bool PVK>
__global__ __launch_bounds__(256, 4) void gemm_db_kernel(
    const unsigned short* __restrict__ Ah, const unsigned short* __restrict__ Bh,
    size_t lda, size_t ldb, int K,
    float* __restrict__ Cf, unsigned short* __restrict__ Ch, size_t ldc,
    size_t abatch, size_t bbatch, size_t cbatch) {
  constexpr int TILE = 128 * 32;                 // 4096 shorts = 8KB
  __shared__ unsigned short smem[2][2 * TILE];   // 32KB

  // Bijective XCD-chunked swizzle over the full linearized grid (m204).
  int lid = blockIdx.x + gridDim.x * (blockIdx.y + gridDim.y * blockIdx.z);
  {
    const int n = gridDim.x * gridDim.y * gridDim.z;
    const int q = n >> 3, r = n & 7, x = lid & 7, k = lid >> 3;
    lid = (x < r ? x * (q + 1) : r * (q + 1) + (x - r) * q) + k;
  }
  int bm, bn, b;
  if constexpr (PACKED) {
    const int t = lid % gridDim.x;
    b = lid / gridDim.x;
    bm = (int)((sqrtf(8.f * (float)t + 1.f) - 1.f) * 0.5f);
    while ((bm + 1) * (bm + 2) / 2 <= t) ++bm;
    while (bm * (bm + 1) / 2 > t) --bm;
    bn = t - bm * (bm + 1) / 2;
  } else {
    bn = lid % gridDim.x;
    const int tmp = lid / gridDim.x;
    bm = tmp % gridDim.y;
    b = tmp / gridDim.y;
    if constexpr (PVK) bm = (int)gridDim.y - 1 - bm;  // heavy tiles first
  }
  const int tid = threadIdx.x, lane = tid & 63, wave = tid >> 6;
  const unsigned short* gA = Ah + abatch * b + (size_t)(bm * 128) * lda;
  const unsigned short* gB = Bh + bbatch * b + (size_t)(bn * 128) * ldb;
  const int kend = PVK ? (bm + 1) * 128 : K;
  const int nsteps = kend / 32;
  f32x4 acc[4][4] = {};
  const int wr = (wave >> 1) << 6, wc = (wave & 1) << 6;
  const int frow = lane & 15, koff = (lane >> 4) << 3;

  auto stage_all = [&](unsigned short* buf, int k0) {
    stage32(buf, gA, lda, k0, wave, lane);
    stage32(buf + TILE, gB, ldb, k0, wave, lane);
  };

  stage_all(smem[0], 0);
  if (nsteps > 1) stage_all(smem[1], 32);
  int cur = 0;
  for (int st = 0; st < nsteps; ++st) {
    if (st + 1 < nsteps) {
      asm volatile("s_waitcnt vmcnt(4)" ::: "memory");
    } else {
      asm volatile("s_waitcnt vmcnt(0)" ::: "memory");
    }
    __builtin_amdgcn_sched_barrier(0);
    __builtin_amdgcn_s_barrier();  // buf[cur] fully in LDS (all waves)
    __builtin_amdgcn_sched_barrier(0);
    const unsigned short* sA = smem[cur];
    const unsigned short* sB = smem[cur] + TILE;
    f16x8 fB[4];
#pragma unroll
    for (int j = 0; j < 4; ++j) fB[j] = frag32(sB, wc + j * 16 + frow, koff);
#pragma unroll
    for (int i = 0; i < 4; ++i) {
      const f16x8 a = frag32(sA, wr + i * 16 + frow, koff);
#pragma unroll
      for (int j = 0; j < 4; ++j) acc[i][j] = mfma_f16(a, fB[j], acc[i][j]);
    }
    asm volatile("s_waitcnt lgkmcnt(0)" ::: "memory");
    __builtin_amdgcn_sched_barrier(0);
    __builtin_amdgcn_s_barrier();  // all waves done reading buf[cur]
    __builtin_amdgcn_sched_barrier(0);
    if (st + 2 < nsteps) stage_all(smem[cur], (st + 2) * 32);
    cur ^= 1;
  }

  const int erow = bm * 128 + wr + ((lane >> 4) << 2);
  const int ecol = bn * 128 + wc + frow;
  if constexpr (EPI == 0) {
    float* C = Cf + cbatch * b;
#pragma unroll
    for (int i = 0; i < 4; ++i)
#pragma unroll
      for (int j = 0; j < 4; ++j)
#pragma unroll
        for (int e = 0; e < 4; ++e)
          C[(size_t)(erow + i * 16 + e) * ldc + (ecol + j * 16)] = acc[i][j][e];
  } else if constexpr (EPI == 3) {
    // Fused V-transpose: Ch is VT[4][1024 o][2048 s].
#pragma unroll
    for (int i = 0; i < 4; ++i)
#pragma unroll
      for (int j = 0; j < 4; ++j) {
        const int s = erow + i * 16;
        const int o = ecol + j * 16;
        u16x4 v;
#pragma unroll
        for (int e = 0; e < 4; ++e) v[e] = f2h(acc[i][j][e]);
        *(u16x4*)&Ch[((size_t)(s >> 11) * 1024 + o) * 2048 + (s & 2047)] = v;
      }
  } else {
    unsigned short* Cho = Ch + cbatch * b;
#pragma unroll
    for (int i = 0; i < 4; ++i)
#pragma unroll
      for (int j = 0; j < 4; ++j)
#pragma unroll
        for (int e = 0; e < 4; ++e)
          Cho[(size_t)(erow + i * 16 + e) * ldc + (ecol + j * 16)] =
              f2h(acc[i][j][e]);
  }
}

// ---------------------------------------------------------------------------
// Sum 4 split-K partials of MT (f32) -> MT plain f16. [1024x1024]
// ---------------------------------------------------------------------------
__global__ __launch_bounds__(256) void reduce_mt_kernel(
    const float* __restrict__ P, unsigned short* __restrict__ H) {
  const size_t base = ((size_t)blockIdx.x * 256 + threadIdx.x) * 4;
  f32x4 s = *(const f32x4*)&P[base];
#pragma unroll
  for (int z = 1; z < 4; ++z) {
    f32x4 v = *(const f32x4*)&P[(size_t)z * 1048576 + base];
    s[0] += v[0]; s[1] += v[1]; s[2] += v[2]; s[3] += v[3];
  }
  u16x4 h;
#pragma unroll
  for (int e = 0; e < 4; ++e) h[e] = f2h(s[e]);
  *(u16x4*)&H[base] = h;
}

// ---------------------------------------------------------------------------
// Row softmax with causal mask + 1/sqrt(d) scale. Writes f16 P in-place
// over the f32 scores buffer. Safe: reads complete before first barrier.
// ---------------------------------------------------------------------------
__global__ __launch_bounds__(256) void softmax_kernel(float* __restrict__ Sc) {
  const int row = blockIdx.x;  // b*2048 + q
  const int q = row & 2047;
  const int tid = threadIdx.x, lane = tid & 63, wave = tid >> 6;
  float* srow = Sc + (size_t)row * 2048;
  unsigned short* prow = (unsigned short*)srow;
  const int k0 = tid * 4, k1 = 1024 + tid * 4;
  f32x4 v0 = {}, v1 = {};
  if (k0 <= q) v0 = *(const f32x4*)(srow + k0);
  if (k1 <= q) v1 = *(const f32x4*)(srow + k1);
  float m = -3.0e38f;
#pragma unroll
  for (int e = 0; e < 4; ++e) {
    if (k0 + e <= q) m = fmaxf(m, v0[e]);
    if (k1 + e <= q) m = fmaxf(m, v1[e]);
  }
#pragma unroll
  for (int o = 32; o; o >>= 1) m = fmaxf(m, __shfl_xor(m, o));
  __shared__ float redm[4], reds[4];
  if (lane == 0) redm[wave] = m;
  __syncthreads();
  m = fmaxf(fmaxf(redm[0], redm[1]), fmaxf(redm[2], redm[3]));
  const float scale = 0.03125f;  // 1/sqrt(1024)
  float p[8];
  float s = 0.f;
#pragma unroll
  for (int e = 0; e < 4; ++e) {
    p[e] = (k0 + e <= q) ? __expf((v0[e] - m) * scale) : 0.f;
    p[4 + e] = (k1 + e <= q) ? __expf((v1[e] - m) * scale) : 0.f;
    s += p[e] + p[4 + e];
  }
#pragma unroll
  for (int o = 32; o; o >>= 1) s += __shfl_xor(s, o);
  if (lane == 0) reds[wave] = s;
  __syncthreads();
  s = reds[0] + reds[1] + reds[2] + reds[3];
  const float inv = 1.0f / s;
  u16x4 o0, o1;
#pragma unroll
  for (int e = 0; e < 4; ++e) {
    o0[e] = f2h(p[e] * inv);
    o1[e] = f2h(p[4 + e] * inv);
  }
  *(u16x4*)&prow[k0] = o0;
  *(u16x4*)&prow[k1] = o1;
}

// ---------------------------------------------------------------------------
extern "C" void kernel_launch(void* const* d_in, const int* in_sizes, int n_in,
                              void* d_out, int out_size, void* d_ws, size_t ws_size,
                              hipStream_t stream) {
  const float* Xk = (const float*)d_in[0];
  const float* Xv = (const float*)d_in[1];
  const float* Xq = (const float*)d_in[2];
  const float* Wk = (const float*)d_in[3];
  const float* Wv = (const float*)d_in[4];
  const float* Wq = (const float*)d_in[5];
  float* out = (float*)d_out;

  char* ws = (char*)d_ws;
  const size_t MB = 1024ull * 1024;
  // Liveness: everything in [0,64MB) is dead before scores -> Sc alias.
  unsigned short* Xqh   = (unsigned short*)(ws + 0);          // 16MB f16, dead after T
  unsigned short* Xvh   = (unsigned short*)(ws + 16 * MB);    // 16MB f16, dead after V
  unsigned short* Wkh   = (unsigned short*)(ws + 32 * MB);    // 2MB f16, dead after M
  unsigned short* Wqh   = (unsigned short*)(ws + 34 * MB);    // 2MB f16, dead after M
  unsigned short* MTh   = (unsigned short*)(ws + 40 * MB);    // 2MB f16, dead after T
  unsigned short* WvT   = (unsigned short*)(ws + 44 * MB);    // 2MB f16, dead after V
  float*          MTpart= (float*)(ws + 46 * MB);             // 16MB f32, dead after reduce
  unsigned short* Xkh   = (unsigned short*)(ws + 64 * MB);    // 16MB f16, live thru scores
  unsigned short* Th    = (unsigned short*)(ws + 80 * MB);    // 16MB f16, live thru scores
  unsigned short* VT    = (unsigned short*)(ws + 96 * MB);    // 16MB f16, live thru PV
  float*          Sc    = (float*)(ws + 0);                   // 64MB alias over dead region

  // --- precision prep (all f16) ---
  convert_wkq_kernel<<<dim3(256, 1, 2), 256, 0, stream>>>(Wk, Wq, Wkh, Wqh);
  convert_wv_kernel<<<dim3(16, 16), 256, 0, stream>>>(Wv, WvT);
  convert_x_kernel<<<dim3(2048, 1, 3), 256, 0, stream>>>(Xk, Xq, Xv, Xkh, Xqh, Xvh);

  // --- M^T = Wk_f16 . Wq_f16^T, split-K over 4 256-wide slices ---
  gemm_db_kernel<0, false, false><<<dim3(8, 8, 4), 256, 0, stream>>>(
      Wkh, Wqh, 1024, 1024, 256, MTpart, nullptr, 1024, 256, 256,
      (size_t)1024 * 1024);
  reduce_mt_kernel<<<dim3(1024), 256, 0, stream>>>(MTpart, MTh);

  // --- T = Xq_f16 . MT^T (f16 out) ---
  gemm_db_kernel<2, false, false><<<dim3(8, 64, 1), 256, 0, stream>>>(
      Xqh, MTh, 1024, 1024, 1024, nullptr, Th, 1024, 0, 0, 0);

  // --- V = Xv . Wv, epilogue writes VT (f16) directly ---
  gemm_db_kernel<3, false, false><<<dim3(8, 64, 1), 256, 0, stream>>>(
      Xvh, WvT, 1024, 1024, 1024, nullptr, VT, 2048, 0, 0, 0);

  // --- scores = T_f16 . Xk_f16^T, packed lower-triangle, f32 out ---
  gemm_db_kernel<0, true, false><<<dim3(136, 1, 4), 256, 0, stream>>>(
      Th, Xkh, 1024, 1024, 1024, Sc, nullptr, 2048, (size_t)2048 * 1024,
      (size_t)2048 * 1024, (size_t)2048 * 2048);

  softmax_kernel<<<dim3(8192), 256, 0, stream>>>(Sc);

  // --- out = P_f16 . V, P pitch 4096, VT K-major, K stops at diagonal;
  //     heavy (large-bm) tiles dispatch first ---
  gemm_db_kernel<0, false, true><<<dim3(8, 16, 4), 256, 0, stream>>>(
      (const unsigned short*)Sc, VT, 4096, 2048, 2048, out, nullptr, 1024,
      (size_t)2048 * 4096, (size_t)1024 * 2048, (size_t)2048 * 1024);
}

// Round 15
// 176.403 us; speedup vs baseline: 1.4213x; 1.0035x over previous
//
#include <hip/hip_runtime.h>
#include <math.h>

using f32x4  = __attribute__((ext_vector_type(4))) float;
using f16x8  = __attribute__((ext_vector_type(8))) _Float16;
using u16x8  = __attribute__((ext_vector_type(8))) unsigned short;
using u16x4  = __attribute__((ext_vector_type(4))) unsigned short;

static __device__ __forceinline__ unsigned short f2h(float f) {
  _Float16 h = (_Float16)f;
  return __builtin_bit_cast(unsigned short, h);
}

static __device__ __forceinline__ f32x4 mfma_f16(f16x8 a, f16x8 b, f32x4 c) {
  return __builtin_amdgcn_mfma_f32_16x16x32_f16(a, b, c, 0, 0, 0);
}

// async global->LDS, 16B per lane. LDS dest is wave-uniform base; HW appends
// lane*16.
static __device__ __forceinline__ void gll16(const void* g, void* l) {
  using GPtr = const unsigned int __attribute__((address_space(1)))*;
  using LPtr = unsigned int __attribute__((address_space(3)))*;
  __builtin_amdgcn_global_load_lds((GPtr)(unsigned long long)g,
                                   (LPtr)(unsigned)(unsigned long long)l,
                                   16, 0, 0);
}

// ---------- f16 [128][64] tile, XOR slot swizzle (r3+: 0-conflict) ----------
// Rows are 128B lines; 16B slot p = q ^ (row&7). Wave w stages rows
// [32w,32w+32): 4 x gll16. Linear LDS dest + pre-swizzled source (rule #21).
static __device__ __forceinline__ void stage64h(unsigned short* sdst,
                                                const unsigned short* g,
                                                size_t ld, int k0, int wave,
                                                int lane) {
  const int r = lane >> 3, c8 = lane & 7;
  const int scol = (c8 ^ r) << 3;
#pragma unroll
  for (int i = 0; i < 4; ++i)
    gll16(g + (size_t)(wave * 32 + i * 8 + r) * ld + (k0 + scol),
          sdst + wave * 2048 + i * 512);
}
static __device__ __forceinline__ f16x8 frag64h(const unsigned short* s,
                                                int row, int kko) {
  return *(const f16x8*)&s[row * 64 + (kko ^ ((row & 7) << 3))];
}

// ---------- f16 [128][32] tile, paired-row layout (r7: 0-conflict) ----------
// 64 lines x 128B; line L holds rows {2L,2L+1}; q = (row&1)<<2 | kblock;
// p = q ^ (L&7). Wave w stages lines [16w,16w+16): 2 x gll16.
static __device__ __forceinline__ void stage32h(unsigned short* sdst,
                                                const unsigned short* g,
                                                size_t ld, int k0, int wave,
                                                int lane) {
  const int p = lane & 7, ll = lane >> 3;
#pragma unroll
  for (int i = 0; i < 2; ++i) {
    const int line = wave * 16 + i * 8 + ll;
    const int q = p ^ (line & 7);
    gll16(g + (size_t)(2 * line + (q >> 2)) * ld + (k0 + ((q & 3) << 3)),
          sdst + wave * 1024 + i * 512);
  }
}
static __device__ __forceinline__ f16x8 frag32h(const unsigned short* s,
                                                int row, int kko) {
  const int line = row >> 1;
  const int q = ((row & 1) << 2) | (kko >> 3);
  const int p = q ^ (line & 7);
  return *(const f16x8*)&s[line * 64 + p * 8];
}

// ---------- f32 [128][32] tile, XOR slot swizzle (row = 128B line) ----------
// Same bank geometry as the f16 [128][64] tile (r3-proven). Wave w stages
// rows [32w,32w+32): 4 x gll16. Fragment read converts f32->f16 in-register
// (RNE, bit-identical to a separate convert kernel).
static __device__ __forceinline__ void stage32f(float* dst, const float* g,
                                                size_t ld, int k0, int wave,
                                                int lane) {
  const int c8 = lane & 7, lr = lane >> 3;
#pragma unroll
  for (int i = 0; i < 4; ++i) {
    const int row = wave * 32 + i * 8 + lr;
    const int q = c8 ^ (row & 7);
    gll16(g + (size_t)row * ld + (k0 + (q << 2)), dst + wave * 1024 + i * 256);
  }
}
static __device__ __forceinline__ f16x8 frag32f(const float* s, int row,
                                                int koff) {
  const int r7 = row & 7;
  const int q0 = koff >> 2;  // koff in {0,8,16,24} -> q0 {0,2,4,6}
  f32x4 lo = *(const f32x4*)&s[row * 32 + ((q0 ^ r7) << 2)];
  f32x4 hi = *(const f32x4*)&s[row * 32 + (((q0 + 1) ^ r7) << 2)];
  f16x8 o;
#pragma unroll
  for (int e = 0; e < 4; ++e) {
    o[e] = (_Float16)lo[e];
    o[4 + e] = (_Float16)hi[e];
  }
  return o;
}

// ---------------------------------------------------------------------------
// Wk/Wq [1024x1024] f32 -> f16, original layout, coalesced.
// ---------------------------------------------------------------------------
__global__ __launch_bounds__(256) void convert_wkq_kernel(
    const float* __restrict__ Wk, const float* __restrict__ Wq,
    unsigned short* __restrict__ Wkh, unsigned short* __restrict__ Wqh) {
  const int z = blockIdx.z;
  const float* W = z ? Wq : Wk;
  unsigned short* H = z ? Wqh : Wkh;
  const size_t base = (size_t)blockIdx.x * 4096 + threadIdx.x * 4;
  f32x4 v[4];
#pragma unroll
  for (int k = 0; k < 4; ++k) v[k] = *(const f32x4*)&W[base + k * 1024];
#pragma unroll
  for (int k = 0; k < 4; ++k) {
    u16x4 h;
#pragma unroll
    for (int e = 0; e < 4; ++e) h[e] = f2h(v[k][e]);
    *(u16x4*)&H[base + k * 1024] = h;
  }
}

// ---------------------------------------------------------------------------
// Wv [1024 i][1024 o] f32 -> WvT [1024 o][1024 i] f16 (transposed)
// ---------------------------------------------------------------------------
__global__ __launch_bounds__(256) void convert_wv_kernel(
    const float* __restrict__ Wv, unsigned short* __restrict__ WvT) {
  __shared__ float sW[64][65];
  const int ti = blockIdx.x * 64;
  const int tj = blockIdx.y * 64;
  const int tid = threadIdx.x;
#pragma unroll
  for (int it = 0; it < 4; ++it) {
    int idx = tid + it * 256;
    int r = idx >> 4, c = (idx & 15) << 2;
    f32x4 v = *(const f32x4*)&Wv[(size_t)(ti + r) * 1024 + tj + c];
    sW[r][c] = v[0]; sW[r][c + 1] = v[1]; sW[r][c + 2] = v[2]; sW[r][c + 3] = v[3];
  }
  __syncthreads();
#pragma unroll
  for (int it = 0; it < 4; ++it) {
    int idx = tid + it * 256;
    int ro = idx >> 4, ci = (idx & 15) << 2;
    u16x4 h;
#pragma unroll
    for (int e = 0; e < 4; ++e) h[e] = f2h(sW[ci + e][ro]);
    *(u16x4*)&WvT[(size_t)(tj + ro) * 1024 + ti + ci] = h;
  }
}

// ---------------------------------------------------------------------------
// Xk [8192 x 1024] f32 -> f16 (only K needs a standalone convert now).
// ---------------------------------------------------------------------------
__global__ __launch_bounds__(256) void convert_xk_kernel(
    const float* __restrict__ Xk, unsigned short* __restrict__ Xkh) {
  const size_t base = (size_t)blockIdx.x * 4096 + threadIdx.x * 4;
  f32x4 v[4];
#pragma unroll
  for (int k = 0; k < 4; ++k) v[k] = *(const f32x4*)&Xk[base + k * 1024];
#pragma unroll
  for (int k = 0; k < 4; ++k) {
    u16x4 h;
#pragma unroll
    for (int e = 0; e < 4; ++e) h[e] = f2h(v[k][e]);
    *(u16x4*)&Xkh[base + k * 1024] = h;
  }
}

// ---------------------------------------------------------------------------
// f16 GEMM (r12-verified): BK=64, 2-buffer counted-vmcnt pipeline, 64KB LDS,
// 2 blocks/CU. Per step: vmcnt(8) -> s_barrier -> ds_read + 32 MFMA ->
// lgkmcnt(0) -> s_barrier -> restage for st+2. XCD swizzle (T1, m204).
// C = A * B^T, both K-major f16.
// EPI: 0 = f32 C ; 2 = f16 C. PACKED: packed lower-triangle tile index.
// PVK: K ends at (bm+1)*128, bm decode reversed (heavy first).
// ---------------------------------------------------------------------------
template <int EPI, bool PACKED, bool PVK>
__global__ __launch_bounds__(256, 2) void gemm_db_kernel(
    const unsigned short* __restrict__ Ah, const unsigned short* __restrict__ Bh,
    size_t lda, size_t ldb, int K,
    float* __restrict__ Cf, unsigned short* __restrict__ Ch, size_t ldc,
    size_t abatch, size_t bbatch, size_t cbatch) {
  constexpr int TILE = 128 * 64;                 // 8192 shorts = 16KB
  __shared__ unsigned short smem[2][2 * TILE];   // 64KB

  int lid = blockIdx.x + gridDim.x * (blockIdx.y + gridDim.y * blockIdx.z);
  {
    const int n = gridDim.x * gridDim.y * gridDim.z;
    const int q = n >> 3, r = n & 7, x = lid & 7, k = lid >> 3;
    lid = (x < r ? x * (q + 1) : r * (q + 1) + (x - r) * q) + k;
  }
  int bm, bn, b;
  if constexpr (PACKED) {
    const int t = lid % gridDim.x;
    b = lid / gridDim.x;
    bm = (int)((sqrtf(8.f * (float)t + 1.f) - 1.f) * 0.5f);
    while ((bm + 1) * (bm + 2) / 2 <= t) ++bm;
    while (bm * (bm + 1) / 2 > t) --bm;
    bn = t - bm * (bm + 1) / 2;
  } else {
    bn = lid % gridDim.x;
    const int tmp = lid / gridDim.x;
    bm = tmp % gridDim.y;
    b = tmp / gridDim.y;
    if constexpr (PVK) bm = (int)gridDim.y - 1 - bm;  // heavy tiles first
  }
  const int tid = threadIdx.x, lane = tid & 63, wave = tid >> 6;
  const unsigned short* gA = Ah + abatch * b + (size_t)(bm * 128) * lda;
  const unsigned short* gB = Bh + bbatch * b + (size_t)(bn * 128) * ldb;
  const int kend = PVK ? (bm + 1) * 128 : K;
  const int nsteps = kend / 64;
  f32x4 acc[4][4] = {};
  const int wr = (wave >> 1) << 6, wc = (wave & 1) << 6;
  const int frow = lane & 15, koff = (lane >> 4) << 3;

  auto stage_all = [&](unsigned short* buf, int k0) {
    stage64h(buf, gA, lda, k0, wave, lane);
    stage64h(buf + TILE, gB, ldb, k0, wave, lane);
  };

  stage_all(smem[0], 0);
  if (nsteps > 1) stage_all(smem[1], 64);
  int cur = 0;
  for (int st = 0; st < nsteps; ++st) {
    if (st + 1 < nsteps) {
      asm volatile("s_waitcnt vmcnt(8)" ::: "memory");
    } else {
      asm volatile("s_waitcnt vmcnt(0)" ::: "memory");
    }
    __builtin_amdgcn_sched_barrier(0);
    __builtin_amdgcn_s_barrier();  // buf[cur] fully in LDS (all waves)
    __builtin_amdgcn_sched_barrier(0);
    const unsigned short* sA = smem[cur];
    const unsigned short* sB = smem[cur] + TILE;
#pragma unroll
    for (int kk = 0; kk < 64; kk += 32) {
      const int kko = kk + koff;
      f16x8 fB[4];
#pragma unroll
      for (int j = 0; j < 4; ++j) fB[j] = frag64h(sB, wc + j * 16 + frow, kko);
#pragma unroll
      for (int i = 0; i < 4; ++i) {
        const f16x8 a = frag64h(sA, wr + i * 16 + frow, kko);
#pragma unroll
        for (int j = 0; j < 4; ++j) acc[i][j] = mfma_f16(a, fB[j], acc[i][j]);
      }
    }
    asm volatile("s_waitcnt lgkmcnt(0)" ::: "memory");
    __builtin_amdgcn_sched_barrier(0);
    __builtin_amdgcn_s_barrier();  // all waves done reading buf[cur]
    __builtin_amdgcn_sched_barrier(0);
    if (st + 2 < nsteps) stage_all(smem[cur], (st + 2) * 64);
    cur ^= 1;
  }

  const int erow = bm * 128 + wr + ((lane >> 4) << 2);
  const int ecol = bn * 128 + wc + frow;
  if constexpr (EPI == 0) {
    float* C = Cf + cbatch * b;
#pragma unroll
    for (int i = 0; i < 4; ++i)
#pragma unroll
      for (int j = 0; j < 4; ++j)
#pragma unroll
        for (int e = 0; e < 4; ++e)
          C[(size_t)(erow + i * 16 + e) * ldc + (ecol + j * 16)] = acc[i][j][e];
  } else {
    unsigned short* Cho = Ch + cbatch * b;
#pragma unroll
    for (int i = 0; i < 4; ++i)
#pragma unroll
      for (int j = 0; j < 4; ++j)
#pragma unroll
        for (int e = 0; e < 4; ++e)
          Cho[(size_t)(erow + i * 16 + e) * ldc + (ecol + j * 16)] =
              f2h(acc[i][j][e]);
  }
}

// ---------------------------------------------------------------------------
// Fused-convert GEMM: A is f32 (staged as f32 tiles, converted on fragment
// read), B is f16. BK=32, 48KB LDS -> 3 blocks/CU. 6 loads/wave/step ->
// vmcnt(6); same verified barrier discipline. C = A * B^T. Single batch.
// EPI: 2 = f16 C ; 3 = f16 transposed into VT[4][1024][2048].
// ---------------------------------------------------------------------------
template <int EPI>
__global__ __launch_bounds__(256, 3) void gemm_cvta_kernel(
    const float* __restrict__ Af, const unsigned short* __restrict__ Bh,
    size_t lda, size_t ldb, int K, unsigned short* __restrict__ Ch,
    size_t ldc) {
  __shared__ float sA[2][128 * 32];           // 16KB each
  __shared__ unsigned short sB[2][128 * 32];  // 8KB each; total 48KB

  int lid = blockIdx.x + gridDim.x * blockIdx.y;
  {
    const int n = gridDim.x * gridDim.y;
    const int q = n >> 3, r = n & 7, x = lid & 7, k = lid >> 3;
    lid = (x < r ? x * (q + 1) : r * (q + 1) + (x - r) * q) + k;
  }
  const int bn = lid % gridDim.x;
  const int bm = lid / gridDim.x;
  const int tid = threadIdx.x, lane = tid & 63, wave = tid >> 6;
  const float* gA = Af + (size_t)(bm * 128) * lda;
  const unsigned short* gB = Bh + (size_t)(bn * 128) * ldb;
  const int nsteps = K / 32;
  f32x4 acc[4][4] = {};
  const int wr = (wave >> 1) << 6, wc = (wave & 1) << 6;
  const int frow = lane & 15, koff = (lane >> 4) << 3;

  auto stage_all = [&](int buf, int k0) {
    stage32f(sA[buf], gA, lda, k0, wave, lane);   // 4 loads
    stage32h(sB[buf], gB, ldb, k0, wave, lane);   // 2 loads
  };

  stage_all(0, 0);
  stage_all(1, 32);  // nsteps >= 8 always
  int cur = 0;
  for (int st = 0; st < nsteps; ++st) {
    if (st + 1 < nsteps) {
      asm volatile("s_waitcnt vmcnt(6)" ::: "memory");
    } else {
      asm volatile("s_waitcnt vmcnt(0)" ::: "memory");
    }
    __builtin_amdgcn_sched_barrier(0);
    __builtin_amdgcn_s_barrier();  // buf[cur] fully in LDS (all waves)
    __builtin_amdgcn_sched_barrier(0);
    f16x8 fB[4];
#pragma unroll
    for (int j = 0; j < 4; ++j) fB[j] = frag32h(sB[cur], wc + j * 16 + frow, koff);
#pragma unroll
    for (int i = 0; i < 4; ++i) {
      const f16x8 a = frag32f(sA[cur], wr + i * 16 + frow, koff);
#pragma unroll
      for (int j = 0; j < 4; ++j) acc[i][j] = mfma_f16(a, fB[j], acc[i][j]);
    }
    asm volatile("s_waitcnt lgkmcnt(0)" ::: "memory");
    __builtin_amdgcn_sched_barrier(0);
    __builtin_amdgcn_s_barrier();  // all waves done reading buf[cur]
    __builtin_amdgcn_sched_barrier(0);
    if (st + 2 < nsteps) stage_all(cur, (st + 2) * 32);
    cur ^= 1;
  }

  const int erow = bm * 128 + wr + ((lane >> 4) << 2);
  const int ecol = bn * 128 + wc + frow;
  if constexpr (EPI == 3) {
    // Fused V-transpose: Ch is VT[4][1024 o][2048 s].
#pragma unroll
    for (int i = 0; i < 4; ++i)
#pragma unroll
      for (int j = 0; j < 4; ++j) {
        const int s = erow + i * 16;
        const int o = ecol + j * 16;
        u16x4 v;
#pragma unroll
        for (int e = 0; e < 4; ++e) v[e] = f2h(acc[i][j][e]);
        *(u16x4*)&Ch[((size_t)(s >> 11) * 1024 + o) * 2048 + (s & 2047)] = v;
      }
  } else {
#pragma unroll
    for (int i = 0; i < 4; ++i)
#pragma unroll
      for (int j = 0; j < 4; ++j)
#pragma unroll
        for (int e = 0; e < 4; ++e)
          Ch[(size_t)(erow + i * 16 + e) * ldc + (ecol + j * 16)] =
              f2h(acc[i][j][e]);
  }
}

// ---------------------------------------------------------------------------
// Sum 4 split-K partials of MT (f32) -> MT plain f16. [1024x1024]
// ---------------------------------------------------------------------------
__global__ __launch_bounds__(256) void reduce_mt_kernel(
    const float* __restrict__ P, unsigned short* __restrict__ H) {
  const size_t base = ((size_t)blockIdx.x * 256 + threadIdx.x) * 4;
  f32x4 s = *(const f32x4*)&P[base];
#pragma unroll
  for (int z = 1; z < 4; ++z) {
    f32x4 v = *(const f32x4*)&P[(size_t)z * 1048576 + base];
    s[0] += v[0]; s[1] += v[1]; s[2] += v[2]; s[3] += v[3];
  }
  u16x4 h;
#pragma unroll
  for (int e = 0; e < 4; ++e) h[e] = f2h(s[e]);
  *(u16x4*)&H[base] = h;
}

// ---------------------------------------------------------------------------
// Row softmax with causal mask + 1/sqrt(d) scale. Writes f16 P in-place
// over the f32 scores buffer. Safe: reads complete before first barrier.
// ---------------------------------------------------------------------------
__global__ __launch_bounds__(256) void softmax_kernel(float* __restrict__ Sc) {
  const int row = blockIdx.x;  // b*2048 + q
  const int q = row & 2047;
  const int tid = threadIdx.x, lane = tid & 63, wave = tid >> 6;
  float* srow = Sc + (size_t)row * 2048;
  unsigned short* prow = (unsigned short*)srow;
  const int k0 = tid * 4, k1 = 1024 + tid * 4;
  f32x4 v0 = {}, v1 = {};
  if (k0 <= q) v0 = *(const f32x4*)(srow + k0);
  if (k1 <= q) v1 = *(const f32x4*)(srow + k1);
  float m = -3.0e38f;
#pragma unroll
  for (int e = 0; e < 4; ++e) {
    if (k0 + e <= q) m = fmaxf(m, v0[e]);
    if (k1 + e <= q) m = fmaxf(m, v1[e]);
  }
#pragma unroll
  for (int o = 32; o; o >>= 1) m = fmaxf(m, __shfl_xor(m, o));
  __shared__ float redm[4], reds[4];
  if (lane == 0) redm[wave] = m;
  __syncthreads();
  m = fmaxf(fmaxf(redm[0], redm[1]), fmaxf(redm[2], redm[3]));
  const float scale = 0.03125f;  // 1/sqrt(1024)
  float p[8];
  float s = 0.f;
#pragma unroll
  for (int e = 0; e < 4; ++e) {
    p[e] = (k0 + e <= q) ? __expf((v0[e] - m) * scale) : 0.f;
    p[4 + e] = (k1 + e <= q) ? __expf((v1[e] - m) * scale) : 0.f;
    s += p[e] + p[4 + e];
  }
#pragma unroll
  for (int o = 32; o; o >>= 1) s += __shfl_xor(s, o);
  if (lane == 0) reds[wave] = s;
  __syncthreads();
  s = reds[0] + reds[1] + reds[2] + reds[3];
  const float inv = 1.0f / s;
  u16x4 o0, o1;
#pragma unroll
  for (int e = 0; e < 4; ++e) {
    o0[e] = f2h(p[e] * inv);
    o1[e] = f2h(p[4 + e] * inv);
  }
  *(u16x4*)&prow[k0] = o0;
  *(u16x4*)&prow[k1] = o1;
}

// ---------------------------------------------------------------------------
extern "C" void kernel_launch(void* const* d_in, const int* in_sizes, int n_in,
                              void* d_out, int out_size, void* d_ws, size_t ws_size,
                              hipStream_t stream) {
  const float* Xk = (const float*)d_in[0];
  const float* Xv = (const float*)d_in[1];
  const float* Xq = (const float*)d_in[2];
  const float* Wk = (const float*)d_in[3];
  const float* Wv = (const float*)d_in[4];
  const float* Wq = (const float*)d_in[5];
  float* out = (float*)d_out;

  char* ws = (char*)d_ws;
  const size_t MB = 1024ull * 1024;
  float*          Sc    = (float*)(ws + 0);                   // 64MB scratch
  unsigned short* Xkh   = (unsigned short*)(ws + 64 * MB);    // 16MB f16
  unsigned short* Th    = (unsigned short*)(ws + 80 * MB);    // 16MB f16
  unsigned short* VT    = (unsigned short*)(ws + 96 * MB);    // 16MB f16
  unsigned short* MTh   = (unsigned short*)(ws + 112 * MB);   // 2MB f16
  unsigned short* Wkh   = (unsigned short*)(ws + 114 * MB);   // 2MB f16
  unsigned short* Wqh   = (unsigned short*)(ws + 116 * MB);   // 2MB f16
  unsigned short* WvT   = (unsigned short*)(ws + 118 * MB);   // 2MB f16
  float*          MTpart= (float*)(ws + 120 * MB);            // 16MB f32

  // --- prep (only K input + weights need conversion kernels now) ---
  convert_wkq_kernel<<<dim3(256, 1, 2), 256, 0, stream>>>(Wk, Wq, Wkh, Wqh);
  convert_wv_kernel<<<dim3(16, 16), 256, 0, stream>>>(Wv, WvT);
  convert_xk_kernel<<<dim3(2048), 256, 0, stream>>>(Xk, Xkh);

  // --- M^T = Wk_f16 . Wq_f16^T, split-K over 4 256-wide slices ---
  gemm_db_kernel<0, false, false><<<dim3(8, 8, 4), 256, 0, stream>>>(
      Wkh, Wqh, 1024, 1024, 256, MTpart, nullptr, 1024, 256, 256,
      (size_t)1024 * 1024);
  reduce_mt_kernel<<<dim3(1024), 256, 0, stream>>>(MTpart, MTh);

  // --- T = Xq(f32, fused-convert) . MT^T (f16 out) ---
  gemm_cvta_kernel<2><<<dim3(8, 64), 256, 0, stream>>>(
      Xq, MTh, 1024, 1024, 1024, Th, 1024);

  // --- V = Xv(f32, fused-convert) . Wv, epilogue writes VT directly ---
  gemm_cvta_kernel<3><<<dim3(8, 64), 256, 0, stream>>>(
      Xv, WvT, 1024, 1024, 1024, VT, 2048);

  // --- scores = T_f16 . Xk_f16^T, packed lower-triangle, f32 out ---
  gemm_db_kernel<0, true, false><<<dim3(136, 1, 4), 256, 0, stream>>>(
      Th, Xkh, 1024, 1024, 1024, Sc, nullptr, 2048, (size_t)2048 * 1024,
      (size_t)2048 * 1024, (size_t)2048 * 2048);

  softmax_kernel<<<dim3(8192), 256, 0, stream>>>(Sc);

  // --- out = P_f16 . V, P pitch 4096, VT K-major, K stops at diagonal;
  //     heavy (large-bm) tiles dispatch first ---
  gemm_db_kernel<0, false, true><<<dim3(8, 16, 4), 256, 0, stream>>>(
      (const unsigned short*)Sc, VT, 4096, 2048, 2048, out, nullptr, 1024,
      (size_t)2048 * 4096, (size_t)1024 * 2048, (size_t)2048 * 1024);
}

// Round 16
// 166.184 us; speedup vs baseline: 1.5088x; 1.0615x over previous
//
#include <hip/hip_runtime.h>
#include <math.h>

using f32x4  = __attribute__((ext_vector_type(4))) float;
using f16x8  = __attribute__((ext_vector_type(8))) _Float16;
using u16x8  = __attribute__((ext_vector_type(8))) unsigned short;
using u16x4  = __attribute__((ext_vector_type(4))) unsigned short;

static __device__ __forceinline__ unsigned short f2h(float f) {
  _Float16 h = (_Float16)f;
  return __builtin_bit_cast(unsigned short, h);
}

static __device__ __forceinline__ f32x4 mfma_f16(f16x8 a, f16x8 b, f32x4 c) {
  return __builtin_amdgcn_mfma_f32_16x16x32_f16(a, b, c, 0, 0, 0);
}

// async global->LDS, 16B per lane. LDS dest is wave-uniform base; HW appends
// lane*16.
static __device__ __forceinline__ void gll16(const void* g, void* l) {
  using GPtr = const unsigned int __attribute__((address_space(1)))*;
  using LPtr = unsigned int __attribute__((address_space(3)))*;
  __builtin_amdgcn_global_load_lds((GPtr)(unsigned long long)g,
                                   (LPtr)(unsigned)(unsigned long long)l,
                                   16, 0, 0);
}

// ---------- f16 [128][64] tile, XOR slot swizzle (r3+: 0-conflict) ----------
static __device__ __forceinline__ void stage64h(unsigned short* sdst,
                                                const unsigned short* g,
                                                size_t ld, int k0, int wave,
                                                int lane) {
  const int r = lane >> 3, c8 = lane & 7;
  const int scol = (c8 ^ r) << 3;
#pragma unroll
  for (int i = 0; i < 4; ++i)
    gll16(g + (size_t)(wave * 32 + i * 8 + r) * ld + (k0 + scol),
          sdst + wave * 2048 + i * 512);
}
static __device__ __forceinline__ f16x8 frag64h(const unsigned short* s,
                                                int row, int kko) {
  return *(const f16x8*)&s[row * 64 + (kko ^ ((row & 7) << 3))];
}

// ---------------------------------------------------------------------------
// Wk/Wq [1024x1024] f32 -> f16, original layout, coalesced.
// ---------------------------------------------------------------------------
__global__ __launch_bounds__(256) void convert_wkq_kernel(
    const float* __restrict__ Wk, const float* __restrict__ Wq,
    unsigned short* __restrict__ Wkh, unsigned short* __restrict__ Wqh) {
  const int z = blockIdx.z;
  const float* W = z ? Wq : Wk;
  unsigned short* H = z ? Wqh : Wkh;
  const size_t base = (size_t)blockIdx.x * 4096 + threadIdx.x * 4;
  f32x4 v[4];
#pragma unroll
  for (int k = 0; k < 4; ++k) v[k] = *(const f32x4*)&W[base + k * 1024];
#pragma unroll
  for (int k = 0; k < 4; ++k) {
    u16x4 h;
#pragma unroll
    for (int e = 0; e < 4; ++e) h[e] = f2h(v[k][e]);
    *(u16x4*)&H[base + k * 1024] = h;
  }
}

// ---------------------------------------------------------------------------
// Wv [1024 i][1024 o] f32 -> WvT [1024 o][1024 i] f16 (transposed)
// ---------------------------------------------------------------------------
__global__ __launch_bounds__(256) void convert_wv_kernel(
    const float* __restrict__ Wv, unsigned short* __restrict__ WvT) {
  __shared__ float sW[64][65];
  const int ti = blockIdx.x * 64;
  const int tj = blockIdx.y * 64;
  const int tid = threadIdx.x;
#pragma unroll
  for (int it = 0; it < 4; ++it) {
    int idx = tid + it * 256;
    int r = idx >> 4, c = (idx & 15) << 2;
    f32x4 v = *(const f32x4*)&Wv[(size_t)(ti + r) * 1024 + tj + c];
    sW[r][c] = v[0]; sW[r][c + 1] = v[1]; sW[r][c + 2] = v[2]; sW[r][c + 3] = v[3];
  }
  __syncthreads();
#pragma unroll
  for (int it = 0; it < 4; ++it) {
    int idx = tid + it * 256;
    int ro = idx >> 4, ci = (idx & 15) << 2;
    u16x4 h;
#pragma unroll
    for (int e = 0; e < 4; ++e) h[e] = f2h(sW[ci + e][ro]);
    *(u16x4*)&WvT[(size_t)(tj + ro) * 1024 + ti + ci] = h;
  }
}

// ---------------------------------------------------------------------------
// X [8192 x 1024] f32 -> X_f16, coalesced; loads batched before stores.
// z: 0 = keys, 1 = queries, 2 = values.
// ---------------------------------------------------------------------------
__global__ __launch_bounds__(256) void convert_x_kernel(
    const float* __restrict__ Xk, const float* __restrict__ Xq,
    const float* __restrict__ Xv, unsigned short* __restrict__ Xkh,
    unsigned short* __restrict__ Xqh, unsigned short* __restrict__ Xvh) {
  const int z = blockIdx.z;
  const float* X = (z == 0) ? Xk : (z == 1) ? Xq : Xv;
  unsigned short* H = (z == 0) ? Xkh : (z == 1) ? Xqh : Xvh;
  const size_t base = (size_t)blockIdx.x * 4096 + threadIdx.x * 4;
  f32x4 v[4];
#pragma unroll
  for (int k = 0; k < 4; ++k) v[k] = *(const f32x4*)&X[base + k * 1024];
#pragma unroll
  for (int k = 0; k < 4; ++k) {
    u16x4 h;
#pragma unroll
    for (int e = 0; e < 4; ++e) h[e] = f2h(v[k][e]);
    *(u16x4*)&H[base + k * 1024] = h;
  }
}

// ---------------------------------------------------------------------------
// f16 GEMM (r12-verified): BK=64, 2-buffer counted-vmcnt pipeline, 64KB LDS,
// 2 blocks/CU. Per step: vmcnt(8) -> s_barrier -> ds_read + 32 MFMA ->
// lgkmcnt(0) -> s_barrier -> restage for st+2. XCD swizzle (T1, m204).
// C = A * B^T, both K-major f16.
// EPI: 0 = f32 C ; 2 = f16 C ; 3 = f16 transposed into VT[4][1024][2048].
// PACKED: packed lower-triangle tile index.
// PVK: K ends at (bm+1)*128, bm decode reversed (heavy first).
// ---------------------------------------------------------------------------
template <int EPI, bool PACKED, bool PVK>
__global__ __launch_bounds__(256, 2) void gemm_db_kernel(
    const unsigned short* __restrict__ Ah, const unsigned short* __restrict__ Bh,
    size_t lda, size_t ldb, int K,
    float* __restrict__ Cf, unsigned short* __restrict__ Ch, size_t ldc,
    size_t abatch, size_t bbatch, size_t cbatch) {
  constexpr int TILE = 128 * 64;                 // 8192 shorts = 16KB
  __shared__ unsigned short smem[2][2 * TILE];   // 64KB

  int lid = blockIdx.x + gridDim.x * (blockIdx.y + gridDim.y * blockIdx.z);
  {
    const int n = gridDim.x * gridDim.y * gridDim.z;
    const int q = n >> 3, r = n & 7, x = lid & 7, k = lid >> 3;
    lid = (x < r ? x * (q + 1) : r * (q + 1) + (x - r) * q) + k;
  }
  int bm, bn, b;
  if constexpr (PACKED) {
    const int t = lid % gridDim.x;
    b = lid / gridDim.x;
    bm = (int)((sqrtf(8.f * (float)t + 1.f) - 1.f) * 0.5f);
    while ((bm + 1) * (bm + 2) / 2 <= t) ++bm;
    while (bm * (bm + 1) / 2 > t) --bm;
    bn = t - bm * (bm + 1) / 2;
  } else {
    bn = lid % gridDim.x;
    const int tmp = lid / gridDim.x;
    bm = tmp % gridDim.y;
    b = tmp / gridDim.y;
    if constexpr (PVK) bm = (int)gridDim.y - 1 - bm;  // heavy tiles first
  }
  const int tid = threadIdx.x, lane = tid & 63, wave = tid >> 6;
  const unsigned short* gA = Ah + abatch * b + (size_t)(bm * 128) * lda;
  const unsigned short* gB = Bh + bbatch * b + (size_t)(bn * 128) * ldb;
  const int kend = PVK ? (bm + 1) * 128 : K;
  const int nsteps = kend / 64;
  f32x4 acc[4][4] = {};
  const int wr = (wave >> 1) << 6, wc = (wave & 1) << 6;
  const int frow = lane & 15, koff = (lane >> 4) << 3;

  auto stage_all = [&](unsigned short* buf, int k0) {
    stage64h(buf, gA, lda, k0, wave, lane);
    stage64h(buf + TILE, gB, ldb, k0, wave, lane);
  };

  stage_all(smem[0], 0);
  if (nsteps > 1) stage_all(smem[1], 64);
  int cur = 0;
  for (int st = 0; st < nsteps; ++st) {
    if (st + 1 < nsteps) {
      asm volatile("s_waitcnt vmcnt(8)" ::: "memory");
    } else {
      asm volatile("s_waitcnt vmcnt(0)" ::: "memory");
    }
    __builtin_amdgcn_sched_barrier(0);
    __builtin_amdgcn_s_barrier();  // buf[cur] fully in LDS (all waves)
    __builtin_amdgcn_sched_barrier(0);
    const unsigned short* sA = smem[cur];
    const unsigned short* sB = smem[cur] + TILE;
#pragma unroll
    for (int kk = 0; kk < 64; kk += 32) {
      const int kko = kk + koff;
      f16x8 fB[4];
#pragma unroll
      for (int j = 0; j < 4; ++j) fB[j] = frag64h(sB, wc + j * 16 + frow, kko);
#pragma unroll
      for (int i = 0; i < 4; ++i) {
        const f16x8 a = frag64h(sA, wr + i * 16 + frow, kko);
#pragma unroll
        for (int j = 0; j < 4; ++j) acc[i][j] = mfma_f16(a, fB[j], acc[i][j]);
      }
    }
    asm volatile("s_waitcnt lgkmcnt(0)" ::: "memory");
    __builtin_amdgcn_sched_barrier(0);
    __builtin_amdgcn_s_barrier();  // all waves done reading buf[cur]
    __builtin_amdgcn_sched_barrier(0);
    if (st + 2 < nsteps) stage_all(smem[cur], (st + 2) * 64);
    cur ^= 1;
  }

  const int erow = bm * 128 + wr + ((lane >> 4) << 2);
  const int ecol = bn * 128 + wc + frow;
  if constexpr (EPI == 0) {
    float* C = Cf + cbatch * b;
#pragma unroll
    for (int i = 0; i < 4; ++i)
#pragma unroll
      for (int j = 0; j < 4; ++j)
#pragma unroll
        for (int e = 0; e < 4; ++e)
          C[(size_t)(erow + i * 16 + e) * ldc + (ecol + j * 16)] = acc[i][j][e];
  } else if constexpr (EPI == 3) {
    // Fused V-transpose: Ch is VT[4][1024 o][2048 s].
#pragma unroll
    for (int i = 0; i < 4; ++i)
#pragma unroll
      for (int j = 0; j < 4; ++j) {
        const int s = erow + i * 16;
        const int o = ecol + j * 16;
        u16x4 v;
#pragma unroll
        for (int e = 0; e < 4; ++e) v[e] = f2h(acc[i][j][e]);
        *(u16x4*)&Ch[((size_t)(s >> 11) * 1024 + o) * 2048 + (s & 2047)] = v;
      }
  } else {
    unsigned short* Cho = Ch + cbatch * b;
#pragma unroll
    for (int i = 0; i < 4; ++i)
#pragma unroll
      for (int j = 0; j < 4; ++j)
#pragma unroll
        for (int e = 0; e < 4; ++e)
          Cho[(size_t)(erow + i * 16 + e) * ldc + (ecol + j * 16)] =
              f2h(acc[i][j][e]);
  }
}

// ---------------------------------------------------------------------------
// Sum 4 split-K partials of MT (f32) -> MT plain f16. [1024x1024]
// ---------------------------------------------------------------------------
__global__ __launch_bounds__(256) void reduce_mt_kernel(
    const float* __restrict__ P, unsigned short* __restrict__ H) {
  const size_t base = ((size_t)blockIdx.x * 256 + threadIdx.x) * 4;
  f32x4 s = *(const f32x4*)&P[base];
#pragma unroll
  for (int z = 1; z < 4; ++z) {
    f32x4 v = *(const f32x4*)&P[(size_t)z * 1048576 + base];
    s[0] += v[0]; s[1] += v[1]; s[2] += v[2]; s[3] += v[3];
  }
  u16x4 h;
#pragma unroll
  for (int e = 0; e < 4; ++e) h[e] = f2h(s[e]);
  *(u16x4*)&H[base] = h;
}

// ---------------------------------------------------------------------------
// Row softmax with causal mask + 1/sqrt(d) scale. Reads f32 scores (pitch
// 2048); writes f16 P into DENSE Pd[4][2048][2048] — only cols PV reads
// (col < ((q>>7)+1)*128). Values bit-identical to the in-place variant.
// ---------------------------------------------------------------------------
__global__ __launch_bounds__(256) void softmax_kernel(
    const float* __restrict__ Sc, unsigned short* __restrict__ P) {
  const int row = blockIdx.x;  // b*2048 + q
  const int q = row & 2047;
  const int kendr = ((q >> 7) + 1) << 7;
  const int tid = threadIdx.x, lane = tid & 63, wave = tid >> 6;
  const float* srow = Sc + (size_t)row * 2048;
  unsigned short* prow = P + (size_t)row * 2048;
  const int k0 = tid * 4, k1 = 1024 + tid * 4;
  f32x4 v0 = {}, v1 = {};
  if (k0 <= q) v0 = *(const f32x4*)(srow + k0);
  if (k1 <= q) v1 = *(const f32x4*)(srow + k1);
  float m = -3.0e38f;
#pragma unroll
  for (int e = 0; e < 4; ++e) {
    if (k0 + e <= q) m = fmaxf(m, v0[e]);
    if (k1 + e <= q) m = fmaxf(m, v1[e]);
  }
#pragma unroll
  for (int o = 32; o; o >>= 1) m = fmaxf(m, __shfl_xor(m, o));
  __shared__ float redm[4], reds[4];
  if (lane == 0) redm[wave] = m;
  __syncthreads();
  m = fmaxf(fmaxf(redm[0], redm[1]), fmaxf(redm[2], redm[3]));
  const float scale = 0.03125f;  // 1/sqrt(1024)
  float p[8];
  float s = 0.f;
#pragma unroll
  for (int e = 0; e < 4; ++e) {
    p[e] = (k0 + e <= q) ? __expf((v0[e] - m) * scale) : 0.f;
    p[4 + e] = (k1 + e <= q) ? __expf((v1[e] - m) * scale) : 0.f;
    s += p[e] + p[4 + e];
  }
#pragma unroll
  for (int o = 32; o; o >>= 1) s += __shfl_xor(s, o);
  if (lane == 0) reds[wave] = s;
  __syncthreads();
  s = reds[0] + reds[1] + reds[2] + reds[3];
  const float inv = 1.0f / s;
  if (k0 < kendr) {
    u16x4 o0;
#pragma unroll
    for (int e = 0; e < 4; ++e) o0[e] = f2h(p[e] * inv);
    *(u16x4*)&prow[k0] = o0;
  }
  if (k1 < kendr) {
    u16x4 o1;
#pragma unroll
    for (int e = 0; e < 4; ++e) o1[e] = f2h(p[4 + e] * inv);
    *(u16x4*)&prow[k1] = o1;
  }
}

// ---------------------------------------------------------------------------
extern "C" void kernel_launch(void* const* d_in, const int* in_sizes, int n_in,
                              void* d_out, int out_size, void* d_ws, size_t ws_size,
                              hipStream_t stream) {
  const float* Xk = (const float*)d_in[0];
  const float* Xv = (const float*)d_in[1];
  const float* Xq = (const float*)d_in[2];
  const float* Wk = (const float*)d_in[3];
  const float* Wv = (const float*)d_in[4];
  const float* Wq = (const float*)d_in[5];
  float* out = (float*)d_out;

  char* ws = (char*)d_ws;
  const size_t MB = 1024ull * 1024;
  float*          Sc    = (float*)(ws + 0);                   // 64MB f32 scores
  unsigned short* Xkh   = (unsigned short*)(ws + 64 * MB);    // 16MB f16
  unsigned short* Xqh   = (unsigned short*)(ws + 80 * MB);    // 16MB f16
  unsigned short* Xvh   = (unsigned short*)(ws + 96 * MB);    // 16MB f16
  unsigned short* Th    = (unsigned short*)(ws + 112 * MB);   // 16MB f16
  unsigned short* VT    = (unsigned short*)(ws + 128 * MB);   // 16MB f16
  unsigned short* MTh   = (unsigned short*)(ws + 144 * MB);   // 2MB f16
  unsigned short* Wkh   = (unsigned short*)(ws + 146 * MB);   // 2MB f16
  unsigned short* Wqh   = (unsigned short*)(ws + 148 * MB);   // 2MB f16
  unsigned short* WvT   = (unsigned short*)(ws + 150 * MB);   // 2MB f16
  float*          MTpart= (float*)(ws + 152 * MB);            // 16MB f32
  unsigned short* Pd    = (unsigned short*)(ws + 0);          // 32MB f16 dense P
  // Pd aliases the Sc region's first 32MB: softmax reads Sc row (f32, pitch
  // 2048) then writes Pd row (f16, pitch 2048). Row r of Pd occupies bytes
  // [r*4096, r*4096+4096) = the FIRST HALF of Sc row r (bytes [r*8192,
  // r*8192+8192)) only when r... NOT row-aligned -> use a clean region:
  Pd = (unsigned short*)(ws + 168 * MB);                      // 32MB, no alias

  // --- precision prep (all f16) ---
  convert_wkq_kernel<<<dim3(256, 1, 2), 256, 0, stream>>>(Wk, Wq, Wkh, Wqh);
  convert_wv_kernel<<<dim3(16, 16), 256, 0, stream>>>(Wv, WvT);
  convert_x_kernel<<<dim3(2048, 1, 3), 256, 0, stream>>>(Xk, Xq, Xv, Xkh, Xqh, Xvh);

  // --- M^T = Wk_f16 . Wq_f16^T, split-K over 4 256-wide slices ---
  gemm_db_kernel<0, false, false><<<dim3(8, 8, 4), 256, 0, stream>>>(
      Wkh, Wqh, 1024, 1024, 256, MTpart, nullptr, 1024, 256, 256,
      (size_t)1024 * 1024);
  reduce_mt_kernel<<<dim3(1024), 256, 0, stream>>>(MTpart, MTh);

  // --- T = Xq_f16 . MT^T (f16 out) ---
  gemm_db_kernel<2, false, false><<<dim3(8, 64, 1), 256, 0, stream>>>(
      Xqh, MTh, 1024, 1024, 1024, nullptr, Th, 1024, 0, 0, 0);

  // --- V = Xv . Wv, epilogue writes VT (f16) directly ---
  gemm_db_kernel<3, false, false><<<dim3(8, 64, 1), 256, 0, stream>>>(
      Xvh, WvT, 1024, 1024, 1024, nullptr, VT, 2048, 0, 0, 0);

  // --- scores = T_f16 . Xk_f16^T, packed lower-triangle, f32 out ---
  gemm_db_kernel<0, true, false><<<dim3(136, 1, 4), 256, 0, stream>>>(
      Th, Xkh, 1024, 1024, 1024, Sc, nullptr, 2048, (size_t)2048 * 1024,
      (size_t)2048 * 1024, (size_t)2048 * 2048);

  // --- softmax: f32 scores -> dense f16 P (only PV-read columns) ---
  softmax_kernel<<<dim3(8192), 256, 0, stream>>>(Sc, Pd);

  // --- out = P_f16 (dense, pitch 2048) . V, K stops at diagonal;
  //     heavy (large-bm) tiles dispatch first ---
  gemm_db_kernel<0, false, true><<<dim3(8, 16, 4), 256, 0, stream>>>(
      Pd, VT, 2048, 2048, 2048, out, nullptr, 1024,
      (size_t)2048 * 2048, (size_t)1024 * 2048, (size_t)2048 * 1024);
}

// Round 18
// 164.537 us; speedup vs baseline: 1.5239x; 1.0100x over previous
//
#include <hip/hip_runtime.h>
#include <math.h>

using f32x4  = __attribute__((ext_vector_type(4))) float;
using bf16x8 = __attribute__((ext_vector_type(8))) short;
using f16x8  = __attribute__((ext_vector_type(8))) _Float16;
using u16x8  = __attribute__((ext_vector_type(8))) unsigned short;
using u16x4  = __attribute__((ext_vector_type(4))) unsigned short;

static __device__ __forceinline__ unsigned short f2bf(float f) {
  unsigned int u = __builtin_bit_cast(unsigned int, f);
  u += 0x7FFFu + ((u >> 16) & 1u);
  return (unsigned short)(u >> 16);
}
static __device__ __forceinline__ float bf2f(unsigned short h) {
  unsigned int u = ((unsigned int)h) << 16;
  return __builtin_bit_cast(float, u);
}
static __device__ __forceinline__ unsigned short f2h(float f) {
  _Float16 h = (_Float16)f;
  return __builtin_bit_cast(unsigned short, h);
}

// dtype-dispatched 16x16x32 MFMA (C/D layout is dtype-independent, m89/m121)
template <bool F16>
static __device__ __forceinline__ f32x4 mfma16(bf16x8 a, bf16x8 b, f32x4 c) {
  if constexpr (F16)
    return __builtin_amdgcn_mfma_f32_16x16x32_f16(
        __builtin_bit_cast(f16x8, a), __builtin_bit_cast(f16x8, b), c, 0, 0, 0);
  else
    return __builtin_amdgcn_mfma_f32_16x16x32_bf16(a, b, c, 0, 0, 0);
}
template <bool F16>
static __device__ __forceinline__ unsigned short cvt16(float v) {
  if constexpr (F16) return f2h(v);
  else return f2bf(v);
}

// async global->LDS, 16B per lane. LDS dest is wave-uniform base; HW appends
// lane*16.
static __device__ __forceinline__ void gll16(const void* g, void* l) {
  using GPtr = const unsigned int __attribute__((address_space(1)))*;
  using LPtr = unsigned int __attribute__((address_space(3)))*;
  __builtin_amdgcn_global_load_lds((GPtr)(unsigned long long)g,
                                   (LPtr)(unsigned)(unsigned long long)l,
                                   16, 0, 0);
}

// Stage one [128][BK] 16-bit tile (rule #21: linear LDS dest, pre-swizzled
// global source). Wave w stages rows [32w, 32w+32).
// BK=64: rows are 128B lines; slot (16B) XOR row&7.        [r3+: 0-conflict]
// BK=32: PAIRED-ROW layout — 64 lines x 128B.              [r7: 0-conflict]
// Loads issued per wave per tile: BK=64 -> 4, BK=32 -> 2.
template <int BK>
static __device__ __forceinline__ void stageT(unsigned short* sdst,
                                              const unsigned short* g,
                                              size_t ld, int k0, int wave,
                                              int lane) {
  if constexpr (BK == 64) {
    const int r = lane >> 3, c8 = lane & 7;
    const int scol = (c8 ^ r) << 3;
#pragma unroll
    for (int i = 0; i < 4; ++i)
      gll16(g + (size_t)(wave * 32 + i * 8 + r) * ld + (k0 + scol),
            sdst + wave * 2048 + i * 512);
  } else {
    const int p = lane & 7;    // physical 16B slot in line
    const int ll = lane >> 3;  // local line 0..7
#pragma unroll
    for (int i = 0; i < 2; ++i) {
      const int line = wave * 16 + i * 8 + ll;  // global line 0..63
      const int q = p ^ (line & 7);
      const int srow = 2 * line + (q >> 2);
      const int scol = (q & 3) << 3;
      gll16(g + (size_t)srow * ld + (k0 + scol), sdst + wave * 1024 + i * 512);
    }
  }
}

// Swizzled fragment read matching stageT's layout.
template <int BK>
static __device__ __forceinline__ bf16x8 fragT(const unsigned short* s,
                                               int row, int kko) {
  if constexpr (BK == 64) {
    return *(const bf16x8*)&s[row * 64 + (kko ^ ((row & 7) << 3))];
  } else {
    const int line = row >> 1;
    const int q = ((row & 1) << 2) | (kko >> 3);
    const int p = q ^ (line & 7);
    return *(const bf16x8*)&s[line * 64 + p * 8];
  }
}

// ---------------------------------------------------------------------------
// Wk/Wq [1024x1024] f32 -> f16, original layout, fully coalesced.
// z: 0 = Wk, 1 = Wq. grid (256,1,2), 4096 elems/block.
// ---------------------------------------------------------------------------
__global__ __launch_bounds__(256) void convert_wkq_kernel(
    const float* __restrict__ Wk, const float* __restrict__ Wq,
    unsigned short* __restrict__ Wkh, unsigned short* __restrict__ Wqh) {
  const int z = blockIdx.z;
  const float* W = z ? Wq : Wk;
  unsigned short* H = z ? Wqh : Wkh;
  const size_t base = (size_t)blockIdx.x * 4096 + threadIdx.x * 4;
#pragma unroll
  for (int k = 0; k < 4; ++k) {
    f32x4 v = *(const f32x4*)&W[base + k * 1024];
    u16x4 h;
#pragma unroll
    for (int e = 0; e < 4; ++e) h[e] = f2h(v[e]);
    *(u16x4*)&H[base + k * 1024] = h;
  }
}

// ---------------------------------------------------------------------------
// Wv [1024 i][1024 o] f32 -> WvT [1024 o][1024 i] f16 (transposed)
// ---------------------------------------------------------------------------
__global__ __launch_bounds__(256) void convert_wv_kernel(
    const float* __restrict__ Wv, unsigned short* __restrict__ WvT) {
  __shared__ float sW[64][65];
  const int ti = blockIdx.x * 64;
  const int tj = blockIdx.y * 64;
  const int tid = threadIdx.x;
#pragma unroll
  for (int it = 0; it < 4; ++it) {
    int idx = tid + it * 256;
    int r = idx >> 4, c = (idx & 15) << 2;
    f32x4 v = *(const f32x4*)&Wv[(size_t)(ti + r) * 1024 + tj + c];
    sW[r][c] = v[0]; sW[r][c + 1] = v[1]; sW[r][c + 2] = v[2]; sW[r][c + 3] = v[3];
  }
  __syncthreads();
#pragma unroll
  for (int it = 0; it < 4; ++it) {
    int idx = tid + it * 256;
    int ro = idx >> 4, ci = (idx & 15) << 2;
    u16x4 h;
#pragma unroll
    for (int e = 0; e < 4; ++e) h[e] = f2h(sW[ci + e][ro]);
    *(u16x4*)&WvT[(size_t)(tj + ro) * 1024 + ti + ci] = h;
  }
}

// ---------------------------------------------------------------------------
// X [8192 x 1024] f32 -> X_f16, fully coalesced: lane handles 4 elems per
// instruction, 4 instructions at +1024-elem stride. Every wave load covers
// contiguous 1KB, every store 512B. z: 0 = keys, 1 = queries, 2 = values.
// grid (2048,1,3), 4096 elems/block.
// ---------------------------------------------------------------------------
__global__ __launch_bounds__(256) void convert_x_kernel(
    const float* __restrict__ Xk, const float* __restrict__ Xq,
    const float* __restrict__ Xv, unsigned short* __restrict__ Xkh,
    unsigned short* __restrict__ Xqh, unsigned short* __restrict__ Xvh) {
  const int z = blockIdx.z;
  const float* X = (z == 0) ? Xk : (z == 1) ? Xq : Xv;
  unsigned short* H = (z == 0) ? Xkh : (z == 1) ? Xqh : Xvh;
  const size_t base = (size_t)blockIdx.x * 4096 + threadIdx.x * 4;
#pragma unroll
  for (int k = 0; k < 4; ++k) {
    f32x4 v = *(const f32x4*)&X[base + k * 1024];
    u16x4 h;
#pragma unroll
    for (int e = 0; e < 4; ++e) h[e] = f2h(v[e]);
    *(u16x4*)&H[base + k * 1024] = h;
  }
}

// ---------------------------------------------------------------------------
// Unified 16-bit GEMM, deep 2-buffer counted-vmcnt pipeline (T4, r8-verified):
// prologue stages BOTH buffers; per step: vmcnt(LPS) -> barrier -> MFMA ->
// lgkmcnt(0) -> barrier -> restage for st+2. LPS: NTERMS 3 -> 8, 2 -> 6,
// 1 -> 8. NTERMS==3: BK=32 paired-row, 4 tiles/buf (64KB); NTERMS==2: BK=32,
// 3 tiles/buf (48KB); NTERMS==1: BK=64, 2 tiles/buf (64KB). XCD swizzle (T1).
// Terms: 3 = AhBh+AhBl+AlBh ; 2 = AhBh+AhBl ; 1 = AhBh.
// F16: use f16 MFMA + f16 epilogue converts (else bf16).
// EPI: 0 = f32 C ; 1 = 16b hi+lo ; 2 = 16b hi ; 3 = 16b transposed into
// VT[4][1024][2048] (fused V-transpose).
// PACKED: lid%gx is a packed lower-triangle tile index.
// PVK: K-loop ends at (bm+1)*128; bm decode is REVERSED so heavy tiles
// dispatch first (light diagonal blocks pack the tail).
// ---------------------------------------------------------------------------
template <int NTERMS, int EPI, bool PACKED, bool PVK, bool F16>
__global__ __launch_bounds__(256, 2) void gemm_db_kernel(
    const unsigned short* __restrict__ Ah, const unsigned short* __restrict__ Al,
    const unsigned short* __restrict__ Bh, const unsigned short* __restrict__ Bl,
    size_t lda, size_t ldb, int K,
    float* __restrict__ Cf, unsigned short* __restrict__ Ch,
    unsigned short* __restrict__ Cl, size_t ldc,
    size_t abatch, size_t bbatch, size_t cbatch) {
  constexpr int BK = (NTERMS >= 2) ? 32 : 64;
  constexpr int NTILES = (NTERMS == 3) ? 4 : (NTERMS == 2) ? 3 : 2;
  constexpr int TILE = 128 * BK;  // shorts per tile
  __shared__ unsigned short smem[2][NTILES * TILE];

  // Bijective XCD-chunked swizzle over the full linearized grid (m204).
  int lid = blockIdx.x + gridDim.x * (blockIdx.y + gridDim.y * blockIdx.z);
  {
    const int n = gridDim.x * gridDim.y * gridDim.z;
    const int q = n >> 3, r = n & 7, x = lid & 7, k = lid >> 3;
    lid = (x < r ? x * (q + 1) : r * (q + 1) + (x - r) * q) + k;
  }
  int bm, bn, b;
  if constexpr (PACKED) {
    const int t = lid % gridDim.x;
    b = lid / gridDim.x;
    bm = (int)((sqrtf(8.f * (float)t + 1.f) - 1.f) * 0.5f);
    while ((bm + 1) * (bm + 2) / 2 <= t) ++bm;
    while (bm * (bm + 1) / 2 > t) --bm;
    bn = t - bm * (bm + 1) / 2;
  } else {
    bn = lid % gridDim.x;
    const int tmp = lid / gridDim.x;
    bm = tmp % gridDim.y;
    b = tmp / gridDim.y;
    if constexpr (PVK) bm = (int)gridDim.y - 1 - bm;  // heavy tiles first
  }
  const int tid = threadIdx.x, lane = tid & 63, wave = tid >> 6;
  const unsigned short* gA = Ah + abatch * b + (size_t)(bm * 128) * lda;
  const unsigned short* gB = Bh + bbatch * b + (size_t)(bn * 128) * ldb;
  const unsigned short* gAl2 =
      (NTERMS == 3) ? Al + abatch * b + (size_t)(bm * 128) * lda : nullptr;
  const unsigned short* gBl2 =
      (NTERMS >= 2) ? Bl + bbatch * b + (size_t)(bn * 128) * ldb : nullptr;
  const int kend = PVK ? (bm + 1) * 128 : K;
  const int nsteps = kend / BK;
  f32x4 acc[4][4] = {};
  const int wr = (wave >> 1) << 6, wc = (wave & 1) << 6;
  const int frow = lane & 15, koff = (lane >> 4) << 3;

  auto stage_all = [&](unsigned short* buf, int k0) {
    stageT<BK>(buf, gA, lda, k0, wave, lane);
    stageT<BK>(buf + TILE, gB, ldb, k0, wave, lane);
    if constexpr (NTERMS >= 2) stageT<BK>(buf + 2 * TILE, gBl2, ldb, k0, wave, lane);
    if constexpr (NTERMS == 3) stageT<BK>(buf + 3 * TILE, gAl2, lda, k0, wave, lane);
  };

  stage_all(smem[0], 0);
  if (nsteps > 1) stage_all(smem[1], BK);
  int cur = 0;
  for (int st = 0; st < nsteps; ++st) {
    if (st + 1 < nsteps) {
      if constexpr (NTERMS == 2)
        asm volatile("s_waitcnt vmcnt(6)" ::: "memory");
      else
        asm volatile("s_waitcnt vmcnt(8)" ::: "memory");
    } else {
      asm volatile("s_waitcnt vmcnt(0)" ::: "memory");
    }
    __builtin_amdgcn_sched_barrier(0);
    __builtin_amdgcn_s_barrier();  // buf[cur] fully in LDS (all waves)
    __builtin_amdgcn_sched_barrier(0);
    const unsigned short* sA = smem[cur];
    const unsigned short* sB = smem[cur] + TILE;
    if constexpr (NTERMS >= 2) {
      const unsigned short* sBl = smem[cur] + 2 * TILE;
      const unsigned short* sAl = smem[cur] + 3 * TILE;  // NTERMS==3 only
      bf16x8 fBh[4], fBl[4];
#pragma unroll
      for (int j = 0; j < 4; ++j) {
        fBh[j] = fragT<BK>(sB, wc + j * 16 + frow, koff);
        fBl[j] = fragT<BK>(sBl, wc + j * 16 + frow, koff);
      }
#pragma unroll
      for (int i = 0; i < 4; ++i) {
        const bf16x8 ah = fragT<BK>(sA, wr + i * 16 + frow, koff);
        bf16x8 al = {};
        if constexpr (NTERMS == 3) al = fragT<BK>(sAl, wr + i * 16 + frow, koff);
#pragma unroll
        for (int j = 0; j < 4; ++j) {
          acc[i][j] = mfma16<F16>(ah, fBh[j], acc[i][j]);
          acc[i][j] = mfma16<F16>(ah, fBl[j], acc[i][j]);
          if constexpr (NTERMS == 3)
            acc[i][j] = mfma16<F16>(al, fBh[j], acc[i][j]);
        }
      }
    } else {
#pragma unroll
      for (int kk = 0; kk < 64; kk += 32) {
        const int kko = kk + koff;
        bf16x8 fBh[4];
#pragma unroll
        for (int j = 0; j < 4; ++j) fBh[j] = fragT<BK>(sB, wc + j * 16 + frow, kko);
#pragma unroll
        for (int i = 0; i < 4; ++i) {
          const bf16x8 ah = fragT<BK>(sA, wr + i * 16 + frow, kko);
#pragma unroll
          for (int j = 0; j < 4; ++j)
            acc[i][j] = mfma16<F16>(ah, fBh[j], acc[i][j]);
        }
      }
    }
    asm volatile("s_waitcnt lgkmcnt(0)" ::: "memory");
    __builtin_amdgcn_sched_barrier(0);
    __builtin_amdgcn_s_barrier();  // all waves done reading buf[cur]
    __builtin_amdgcn_sched_barrier(0);
    if (st + 2 < nsteps) stage_all(smem[cur], (st + 2) * BK);
    cur ^= 1;
  }

  const int erow = bm * 128 + wr + ((lane >> 4) << 2);
  const int ecol = bn * 128 + wc + frow;
  if constexpr (EPI == 0) {
    float* C = Cf + cbatch * b;
#pragma unroll
    for (int i = 0; i < 4; ++i)
#pragma unroll
      for (int j = 0; j < 4; ++j)
#pragma unroll
        for (int e = 0; e < 4; ++e)
          C[(size_t)(erow + i * 16 + e) * ldc + (ecol + j * 16)] = acc[i][j][e];
  } else if constexpr (EPI == 3) {
    // Fused V-transpose: Ch is VT[4][1024 o][2048 s].
#pragma unroll
    for (int i = 0; i < 4; ++i)
#pragma unroll
      for (int j = 0; j < 4; ++j) {
        const int s = erow + i * 16;
        const int o = ecol + j * 16;
        u16x4 v;
#pragma unroll
        for (int e = 0; e < 4; ++e) v[e] = cvt16<F16>(acc[i][j][e]);
        *(u16x4*)&Ch[((size_t)(s >> 11) * 1024 + o) * 2048 + (s & 2047)] = v;
      }
  } else {
    unsigned short* Cho = Ch + cbatch * b;
    unsigned short* Clo = (EPI == 1) ? Cl + cbatch * b : nullptr;
#pragma unroll
    for (int i = 0; i < 4; ++i)
#pragma unroll
      for (int j = 0; j < 4; ++j)
#pragma unroll
        for (int e = 0; e < 4; ++e) {
          size_t off = (size_t)(erow + i * 16 + e) * ldc + (ecol + j * 16);
          float v = acc[i][j][e];
          unsigned short hh = cvt16<F16>(v);
          Cho[off] = hh;
          if constexpr (EPI == 1) Clo[off] = f2bf(v - bf2f(hh));
        }
  }
}

// ---------------------------------------------------------------------------
// Sum 4 split-K partials of MT (f32) -> MT plain f16. [1024x1024]
// ---------------------------------------------------------------------------
__global__ __launch_bounds__(256) void reduce_mt_kernel(
    const float* __restrict__ P, unsigned short* __restrict__ H) {
  const size_t base = ((size_t)blockIdx.x * 256 + threadIdx.x) * 4;
  f32x4 s = *(const f32x4*)&P[base];
#pragma unroll
  for (int z = 1; z < 4; ++z) {
    f32x4 v = *(const f32x4*)&P[(size_t)z * 1048576 + base];
    s[0] += v[0]; s[1] += v[1]; s[2] += v[2]; s[3] += v[3];
  }
  u16x4 h;
#pragma unroll
  for (int e = 0; e < 4; ++e) h[e] = f2h(s[e]);
  *(u16x4*)&H[base] = h;
}

// ---------------------------------------------------------------------------
// Row softmax with causal mask + 1/sqrt(d) scale. Writes f16 P in-place
// over the f32 scores buffer. Safe: reads complete before first barrier.
// ---------------------------------------------------------------------------
__global__ __launch_bounds__(256) void softmax_kernel(float* __restrict__ Sc) {
  const int row = blockIdx.x;  // b*2048 + q
  const int q = row & 2047;
  const int tid = threadIdx.x, lane = tid & 63, wave = tid >> 6;
  float* srow = Sc + (size_t)row * 2048;
  unsigned short* prow = (unsigned short*)srow;
  const int k0 = tid * 4, k1 = 1024 + tid * 4;
  f32x4 v0 = {}, v1 = {};
  if (k0 <= q) v0 = *(const f32x4*)(srow + k0);
  if (k1 <= q) v1 = *(const f32x4*)(srow + k1);
  float m = -3.0e38f;
#pragma unroll
  for (int e = 0; e < 4; ++e) {
    if (k0 + e <= q) m = fmaxf(m, v0[e]);
    if (k1 + e <= q) m = fmaxf(m, v1[e]);
  }
#pragma unroll
  for (int o = 32; o; o >>= 1) m = fmaxf(m, __shfl_xor(m, o));
  __shared__ float redm[4], reds[4];
  if (lane == 0) redm[wave] = m;
  __syncthreads();
  m = fmaxf(fmaxf(redm[0], redm[1]), fmaxf(redm[2], redm[3]));
  const float scale = 0.03125f;  // 1/sqrt(1024)
  float p[8];
  float s = 0.f;
#pragma unroll
  for (int e = 0; e < 4; ++e) {
    p[e] = (k0 + e <= q) ? __expf((v0[e] - m) * scale) : 0.f;
    p[4 + e] = (k1 + e <= q) ? __expf((v1[e] - m) * scale) : 0.f;
    s += p[e] + p[4 + e];
  }
#pragma unroll
  for (int o = 32; o; o >>= 1) s += __shfl_xor(s, o);
  if (lane == 0) reds[wave] = s;
  __syncthreads();
  s = reds[0] + reds[1] + reds[2] + reds[3];
  const float inv = 1.0f / s;
  u16x4 o0, o1;
#pragma unroll
  for (int e = 0; e < 4; ++e) {
    o0[e] = f2h(p[e] * inv);
    o1[e] = f2h(p[4 + e] * inv);
  }
  *(u16x4*)&prow[k0] = o0;
  *(u16x4*)&prow[k1] = o1;
}

// ---------------------------------------------------------------------------
extern "C" void kernel_launch(void* const* d_in, const int* in_sizes, int n_in,
                              void* d_out, int out_size, void* d_ws, size_t ws_size,
                              hipStream_t stream) {
  const float* Xk = (const float*)d_in[0];
  const float* Xv = (const float*)d_in[1];
  const float* Xq = (const float*)d_in[2];
  const float* Wk = (const float*)d_in[3];
  const float* Wv = (const float*)d_in[4];
  const float* Wq = (const float*)d_in[5];
  float* out = (float*)d_out;

  char* ws = (char*)d_ws;
  const size_t MB = 1024ull * 1024;
  // Liveness: everything in [0,64MB) is dead before scores -> Sc alias.
  unsigned short* Xqh   = (unsigned short*)(ws + 0);          // 16MB f16, dead after T
  unsigned short* Xvh   = (unsigned short*)(ws + 16 * MB);    // 16MB f16, dead after V
  unsigned short* Wkh   = (unsigned short*)(ws + 32 * MB);    // 2MB f16, dead after M
  unsigned short* Wqh   = (unsigned short*)(ws + 34 * MB);    // 2MB f16, dead after M
  unsigned short* MTh   = (unsigned short*)(ws + 40 * MB);    // 2MB f16, dead after T
  unsigned short* WvT   = (unsigned short*)(ws + 44 * MB);    // 2MB f16, dead after V
  float*          MTpart= (float*)(ws + 46 * MB);             // 16MB f32, dead after reduce
  unsigned short* Xkh   = (unsigned short*)(ws + 64 * MB);    // 16MB f16, live thru scores
  unsigned short* Th    = (unsigned short*)(ws + 80 * MB);    // 16MB f16, live thru scores
  unsigned short* VT    = (unsigned short*)(ws + 96 * MB);    // 16MB f16, live thru PV
  float*          Sc    = (float*)(ws + 0);                   // 64MB alias over dead region

  // --- precision prep (all f16) ---
  convert_wkq_kernel<<<dim3(256, 1, 2), 256, 0, stream>>>(Wk, Wq, Wkh, Wqh);
  convert_wv_kernel<<<dim3(16, 16), 256, 0, stream>>>(Wv, WvT);
  convert_x_kernel<<<dim3(2048, 1, 3), 256, 0, stream>>>(Xk, Xq, Xv, Xkh, Xqh, Xvh);

  // --- M^T = Wk_f16 . Wq_f16^T (1-term f16), split-K over 4 256-wide slices ---
  gemm_db_kernel<1, 0, false, false, true><<<dim3(8, 8, 4), 256, 0, stream>>>(
      Wkh, nullptr, Wqh, nullptr, 1024, 1024, 256, MTpart, nullptr, nullptr,
      1024, 256, 256, (size_t)1024 * 1024);
  reduce_mt_kernel<<<dim3(1024), 256, 0, stream>>>(MTpart, MTh);

  // --- T = Xq_f16 . MT^T (1-term f16, f16 out) ---
  gemm_db_kernel<1, 2, false, false, true><<<dim3(8, 64, 1), 256, 0, stream>>>(
      Xqh, nullptr, MTh, nullptr, 1024, 1024, 1024, nullptr, Th, nullptr,
      1024, 0, 0, 0);

  // --- V = Xv . Wv (1-term f16), epilogue writes VT (f16) directly ---
  gemm_db_kernel<1, 3, false, false, true><<<dim3(8, 64, 1), 256, 0, stream>>>(
      Xvh, nullptr, WvT, nullptr, 1024, 1024, 1024, nullptr, VT, nullptr,
      2048, 0, 0, 0);

  // --- scores = T_f16 . Xk_f16^T (1-term f16), packed lower-triangle ---
  gemm_db_kernel<1, 0, true, false, true><<<dim3(136, 1, 4), 256, 0, stream>>>(
      Th, nullptr, Xkh, nullptr, 1024, 1024, 1024, Sc, nullptr, nullptr, 2048,
      (size_t)2048 * 1024, (size_t)2048 * 1024, (size_t)2048 * 2048);

  softmax_kernel<<<dim3(8192), 256, 0, stream>>>(Sc);

  // --- out = P_f16 . V (f16), P pitch 4096, VT K-major, K stops at diag;
  //     heavy (large-bm) tiles dispatch first ---
  gemm_db_kernel<1, 0, false, true, true><<<dim3(8, 16, 4), 256, 0, stream>>>(
      (const unsigned short*)Sc, nullptr, VT, nullptr, 4096, 2048, 2048,
      out, nullptr, nullptr, 1024, (size_t)2048 * 4096, (size_t)1024 * 2048,
      (size_t)2048 * 1024);
}